// Round 4
// baseline (154734.839 us; speedup 1.0000x reference)
//
#include <hip/hip_runtime.h>
#include <math.h>

// ---------------- config ----------------
#define TF_PARTITIONABLE 1   // jax threefry_partitionable (default True since jax 0.4.36)

static constexpr int Bn=64, Ln=512, En=512, Tn=512, Sn=512, Pn=256, An=1024, Dn=1024, Gn=128, Vn=148;
static constexpr int G4A = 4096;            // 4*A == 4*D
static constexpr int KPROJ = Dn + En;       // 1536
static constexpr int KATT = 1792, KDEC = 2560;
static constexpr int ACH = 4, ACK = 448;    // att gates K = 4 chunks x 448
static constexpr int DCH = 4, DCK = 640;    // dec gates K = 4 chunks x 640
static constexpr int NKB_ATT = KATT / 32;   // 56 k-blocks
static constexpr int NKB_DEC = KDEC / 32;   // 80
static constexpr long LOGITS_OFF = 0;
static constexpr long ALIGNS_OFF = (long)Bn*Tn*Vn;               // 4,849,664
static constexpr long PARAMS_OFF = ALIGNS_OFF + (long)Bn*Tn*Ln;  // 21,626,880

using s16x8 = __attribute__((ext_vector_type(8))) short;
using f32x4 = __attribute__((ext_vector_type(4))) float;

// ---------------- threefry2x32 (jax-exact) ----------------
struct TFo { unsigned a, b; };
static constexpr TFo htf(unsigned k1, unsigned k2, unsigned x0, unsigned x1) {
  unsigned ks2 = k1 ^ k2 ^ 0x1BD11BDAu;
  unsigned ks[3] = {k1, k2, ks2};
  const unsigned ra[4] = {13u,15u,26u,6u}, rb[4] = {17u,29u,16u,24u};
  x0 += k1; x1 += k2;
  for (int g = 0; g < 5; ++g) {
    const unsigned* r = (g % 2 == 0) ? ra : rb;
    for (int i = 0; i < 4; ++i) { x0 += x1; x1 = (x1 << r[i]) | (x1 >> (32u - r[i])); x1 ^= x0; }
    x0 += ks[(g+1)%3]; x1 += ks[(g+2)%3] + (unsigned)(g+1);
  }
  return TFo{x0, x1};
}
#if TF_PARTITIONABLE
static constexpr TFo DK1 = htf(0u,42u,0u,0u);
static constexpr TFo DK2 = htf(0u,42u,0u,1u);
#else
static constexpr TFo S02 = htf(0u,42u,0u,2u);
static constexpr TFo S13 = htf(0u,42u,1u,3u);
static constexpr TFo DK1 = TFo{S02.a, S13.a};
static constexpr TFo DK2 = TFo{S02.b, S13.b};
#endif

__device__ __forceinline__ void dtf(unsigned k1, unsigned k2, unsigned x0, unsigned x1,
                                    unsigned& o0, unsigned& o1) {
  unsigned ks2 = k1 ^ k2 ^ 0x1BD11BDAu;
#define TFR(r) { x0 += x1; x1 = (x1<<r)|(x1>>(32-r)); x1 ^= x0; }
  x0 += k1; x1 += k2;
  TFR(13) TFR(15) TFR(26) TFR(6)  x0 += k2;  x1 += ks2 + 1u;
  TFR(17) TFR(29) TFR(16) TFR(24) x0 += ks2; x1 += k1 + 2u;
  TFR(13) TFR(15) TFR(26) TFR(6)  x0 += k1;  x1 += k2 + 3u;
  TFR(17) TFR(29) TFR(16) TFR(24) x0 += k2;  x1 += ks2 + 4u;
  TFR(13) TFR(15) TFR(26) TFR(6)  x0 += ks2; x1 += k1 + 5u;
#undef TFR
  o0 = x0; o1 = x1;
}

__device__ __forceinline__ bool keepmask(unsigned ka, unsigned kb, unsigned j) {
#if TF_PARTITIONABLE
  unsigned o0, o1; dtf(ka, kb, 0u, j, o0, o1);
  return ((o0 ^ o1) >> 31) == 0u;
#else
  const unsigned H = 4202496u;  // (513*64*256)/2
  unsigned o0, o1;
  if (j < H) { dtf(ka, kb, j, j + H, o0, o1); return (o0 >> 31) == 0u; }
  else       { dtf(ka, kb, j - H, j, o0, o1); return (o1 >> 31) == 0u; }
#endif
}

// ---------------- dtype helpers ----------------
__device__ __forceinline__ float ldbf(const unsigned short* p, long i) {
  return __uint_as_float(((unsigned)p[i]) << 16);
}
__device__ __forceinline__ unsigned short f2bf(float v) {
  unsigned x = __float_as_uint(v);
  return (unsigned short)((x + 0x7fffu + ((x >> 16) & 1u)) >> 16);  // RNE
}
__device__ __forceinline__ void store_out(void* out, long i, float v, int bf) {
  if (bf) ((unsigned short*)out)[i] = f2bf(v);
  else    ((float*)out)[i] = v;
}
__device__ __forceinline__ float st_load(const float* p, long i) { return p[i]; }
__device__ __forceinline__ float st_load(const unsigned short* p, long i) { return ldbf(p, i); }
__device__ __forceinline__ void st_store(float* p, long i, float v) { p[i] = v; }
__device__ __forceinline__ void st_store(unsigned short* p, long i, float v) { p[i] = f2bf(v); }
__device__ __forceinline__ float sigm(float x) { return 1.f / (1.f + expf(-x)); }

// ---------------- pointer pack ----------------
struct Ptrs {
  const float *Wp1,*Wp2,*bai,*bah,*Wg1,*bg1,*Wg2,*bdi,*bdh,*Wpr,*bpr;
  unsigned short *PWatt,*PWdec,*pre_bf,*ah_bf,*ctx_bf,*dh_bf;
  float *Patt,*Pdec,*ah,*ac,*dh,*dc,*ctx,*mean,*alpha_ws;
  int *lws;
  void *dh_all,*ctx_all;
  const void *mem,*din,*w_ai,*w_ah,*w_di,*w_dh;
  const int *mlen; const int *flag; void *out;
};

// ---------------- grid barrier (device-scope, generation-based) ----------------
__device__ __forceinline__ void gsync(int* cnt, int* gen) {
  __syncthreads();
  if (threadIdx.x == 0) {
    __threadfence();   // release this block's writes agent-wide
    int g = __hip_atomic_load(gen, __ATOMIC_RELAXED, __HIP_MEMORY_SCOPE_AGENT);
    int n = (int)gridDim.x;
    int old = __hip_atomic_fetch_add(cnt, 1, __ATOMIC_ACQ_REL, __HIP_MEMORY_SCOPE_AGENT);
    if (old == n - 1) {
      __hip_atomic_store(cnt, 0, __ATOMIC_RELAXED, __HIP_MEMORY_SCOPE_AGENT);
      __hip_atomic_store(gen, g + 1, __ATOMIC_RELEASE, __HIP_MEMORY_SCOPE_AGENT);
    } else {
      long long t0 = clock64();
      while (__hip_atomic_load(gen, __ATOMIC_ACQUIRE, __HIP_MEMORY_SCOPE_AGENT) == g) {
        __builtin_amdgcn_s_sleep(4);
        if (clock64() - t0 > (1LL << 31)) break;   // escape hatch: fail visibly, never hang
      }
    }
    __threadfence();   // acquire side: subsequent loads see remote writes
  }
  __syncthreads();
}

// ---------------- utility kernels ----------------
__global__ __launch_bounds__(256) void k_detect(const void* mem, int* flag) {
  __shared__ int cnt;
  int tid = threadIdx.x;
  if (tid == 0) cnt = 0;
  __syncthreads();
  const unsigned short* p = (const unsigned short*)mem;
  int local = 0;
  for (int i = tid; i < 1024; i += 256) {
    float f = ldbf(p, 2L * i);
    if (f == f && fabsf(f) > 0.0009f && fabsf(f) < 16.f) local++;
  }
  atomicAdd(&cnt, local);
  __syncthreads();
  if (tid == 0) flag[0] = (cnt > 512) ? 1 : 0;
}

__global__ __launch_bounds__(256) void k_convert(const void* src, float* dst, long n, const int* flag) {
  int bf = *flag;
  long i0 = (long)blockIdx.x * 256 + threadIdx.x, stp = (long)gridDim.x * 256;
  if (bf) { const unsigned short* s = (const unsigned short*)src;
            for (long i = i0; i < n; i += stp) dst[i] = ldbf(s, i); }
  else    { const float* s = (const float*)src;
            for (long i = i0; i < n; i += stp) dst[i] = s[i]; }
}

__global__ __launch_bounds__(256) void k_zero_f32(float* p, long n) {
  for (long i = (long)blockIdx.x * 256 + threadIdx.x; i < n; i += (long)gridDim.x * 256) p[i] = 0.f;
}

__global__ __launch_bounds__(256) void k_zero_aligns(void* out, const int* flag) {
  int bf = *flag;
  unsigned* p; long n;
  if (bf) { p = (unsigned*)out + (ALIGNS_OFF >> 1); n = ((long)Bn*Tn*Ln) >> 1; }
  else    { p = (unsigned*)out + ALIGNS_OFF;        n = (long)Bn*Tn*Ln; }
  for (long i = (long)blockIdx.x * 256 + threadIdx.x; i < n; i += (long)gridDim.x * 256) p[i] = 0u;
}

// ---------------- weight packing: bf16 B-fragment order ----------------
// PW[kblk][nblk][lane][8]: lane l elem j <-> W[kblk*32 + (l>>4)*8 + j][nblk*16 + (l&15)]
__global__ __launch_bounds__(256) void k_pack(Ptrs P) {
  __shared__ float s[32][65];
  int bid = blockIdx.x, tid = threadIdx.x;
  bool att = bid < NKB_ATT * 64;
  int lb = att ? bid : bid - NKB_ATT * 64;
  int kblk = lb >> 6, ng = lb & 63;
  int n0 = ng * 64;
  int bf = *P.flag;
  int split = att ? (Pn + En) : (An + En);
  const void* S0 = att ? P.w_ai : P.w_di;
  const void* S1 = att ? P.w_ah : P.w_dh;
  for (int i = tid; i < 2048; i += 256) {
    int kk = i >> 6, n = i & 63;
    int k = kblk * 32 + kk;
    const void* src = (k < split) ? S0 : S1;
    long idx = (long)(k < split ? k : k - split) * G4A + (n0 + n);
    s[kk][n] = bf ? ldbf((const unsigned short*)src, idx) : ((const float*)src)[idx];
  }
  __syncthreads();
  int lane = tid & 63, tb = tid >> 6;
  unsigned short r[8];
#pragma unroll
  for (int j = 0; j < 8; ++j)
    r[j] = f2bf(s[(lane >> 4) * 8 + j][tb * 16 + (lane & 15)]);
  unsigned short* out = (att ? P.PWatt : P.PWdec) +
      (((long)kblk * 256 + (ng * 4 + tb)) * 64 + lane) * 8;
  *(uint4*)out = *(const uint4*)r;
}

// ---------------- prenet (fused GEMM1+mask1+GEMM2+mask2) -> bf16 ----------------
__global__ __launch_bounds__(256) void k_prenet(Ptrs P, unsigned k1a, unsigned k1b,
                                                unsigned k2a, unsigned k2b) {
  __shared__ __align__(16) float x_s[32 * 17];
  __shared__ __align__(16) float W_s[16 * 256];
  __shared__ __align__(16) float h1_s[32 * 258];
  int bid = blockIdx.x, tid = threadIdx.x;
  int t = bid >> 1, half = bid & 1;
  int bf = *P.flag;
  int tc = tid & 63, tr = tid >> 6;
  int p0 = tc * 4, bl0 = tr * 8;
  float acc[8][4];
#pragma unroll
  for (int i = 0; i < 8; ++i) { acc[i][0]=0; acc[i][1]=0; acc[i][2]=0; acc[i][3]=0; }

  for (int kc = 0; kc < 32; ++kc) {
    __syncthreads();
    for (int i = tid; i < 32 * 16; i += 256) {
      int bl = i >> 4, kk = i & 15;
      int s = kc * 16 + kk;
      float v = 0.f;
      if (t > 0) {
        long idx = ((long)(half * 32 + bl) * Sn + s) * Tn + (t - 1);
        v = bf ? ldbf((const unsigned short*)P.din, idx) : ((const float*)P.din)[idx];
      }
      x_s[bl * 17 + kk] = v;
    }
    for (int i = tid; i < 16 * 256; i += 256) {
      int kk = i >> 8, p = i & 255;
      W_s[kk * 256 + p] = P.Wp1[(long)(kc * 16 + kk) * 256 + p];
    }
    __syncthreads();
    for (int kk = 0; kk < 16; ++kk) {
      float4 w = *(const float4*)(W_s + kk * 256 + p0);
#pragma unroll
      for (int i = 0; i < 8; ++i) {
        float x = x_s[(bl0 + i) * 17 + kk];
        acc[i][0] += x * w.x; acc[i][1] += x * w.y; acc[i][2] += x * w.z; acc[i][3] += x * w.w;
      }
    }
  }
#pragma unroll
  for (int i = 0; i < 8; ++i)
#pragma unroll
    for (int j = 0; j < 4; ++j) {
      int bl = bl0 + i, p = p0 + j, bg = half * 32 + bl;
      float v = fmaxf(acc[i][j], 0.f);
      unsigned ft = (unsigned)(((long)t * 64 + bg) * 256 + p);
      v = keepmask(k1a, k1b, ft) ? 2.f * v : 0.f;
      h1_s[bl * 258 + p] = v;
      acc[i][j] = 0.f;
    }
  __syncthreads();
  for (int kc = 0; kc < 16; ++kc) {
    __syncthreads();
    for (int i = tid; i < 16 * 256; i += 256) {
      int kk = i >> 8, p = i & 255;
      W_s[kk * 256 + p] = P.Wp2[(long)(kc * 16 + kk) * 256 + p];
    }
    __syncthreads();
    for (int kk = 0; kk < 16; ++kk) {
      float4 w = *(const float4*)(W_s + kk * 256 + p0);
      int s = kc * 16 + kk;
#pragma unroll
      for (int i = 0; i < 8; ++i) {
        float x = h1_s[(bl0 + i) * 258 + s];
        acc[i][0] += x * w.x; acc[i][1] += x * w.y; acc[i][2] += x * w.z; acc[i][3] += x * w.w;
      }
    }
  }
#pragma unroll
  for (int i = 0; i < 8; ++i)
#pragma unroll
    for (int j = 0; j < 4; ++j) {
      int bg = half * 32 + bl0 + i, p = p0 + j;
      float v = fmaxf(acc[i][j], 0.f);
      unsigned ft = (unsigned)(((long)t * 64 + bg) * 256 + p);
      v = keepmask(k2a, k2b, ft) ? 2.f * v : 0.f;
      P.pre_bf[((long)t * 64 + bg) * 256 + p] = f2bf(v);
    }
}

// ---------------- device phase bodies ----------------
// att gates GEMM (t+1) if vb<256, dec gates GEMM (t) else. MFMA 16x16x32 bf16.
__device__ __forceinline__ void dev_gemm(const Ptrs& P, int t, int vb) {
  bool att = vb < 256;
  if (att) { if (t + 1 >= Tn) return; }
  else     { if (t < 0 || t >= Tn) return; }
  int lb = att ? vb : vb - 256;
  int nb4 = lb >> 2, kc = lb & 3;
  int tid = threadIdx.x;
  int lane = tid & 63, w = tid >> 6;
  int nblk = nb4 * 4 + w;
  const int NK = att ? (ACK / 32) : (DCK / 32);
  const int k0 = kc * (att ? ACK : DCK);
  const unsigned short* PW = att ? P.PWatt : P.PWdec;
  const unsigned short* pre_t = P.pre_bf + (long)(t + 1) * 64 * Pn;

  f32x4 acc[4];
#pragma unroll
  for (int i = 0; i < 4; ++i) acc[i] = f32x4{0.f, 0.f, 0.f, 0.f};

  int rlo = lane & 15, khi = (lane >> 4) * 8;

  auto aseg = [&](int kglob, const unsigned short*& seg, int& stride, int& off) {
    if (att) {
      if (kglob < Pn)            { seg = pre_t;    stride = Pn; off = kglob; }
      else if (kglob < Pn + En)  { seg = P.ctx_bf; stride = En; off = kglob - Pn; }
      else                       { seg = P.ah_bf;  stride = An; off = kglob - Pn - En; }
    } else {
      if (kglob < An)            { seg = P.ah_bf;  stride = An; off = kglob; }
      else if (kglob < An + En)  { seg = P.ctx_bf; stride = En; off = kglob - An; }
      else                       { seg = P.dh_bf;  stride = Dn; off = kglob - An - En; }
    }
  };

  uint4 aN[4], bN;
  {
    const unsigned short* seg; int stride, off;
    aseg(k0, seg, stride, off);
    int kloc = off + khi;
#pragma unroll
    for (int mb = 0; mb < 4; ++mb)
      aN[mb] = *(const uint4*)(seg + (long)(mb * 16 + rlo) * stride + kloc);
    bN = *(const uint4*)(PW + (((long)(k0 >> 5) * 256 + nblk) * 64 + lane) * 8);
  }
  for (int kk = 0; kk < NK; ++kk) {
    uint4 aC[4] = {aN[0], aN[1], aN[2], aN[3]};
    uint4 bC = bN;
    if (kk + 1 < NK) {
      int kglob = k0 + (kk + 1) * 32;
      const unsigned short* seg; int stride, off;
      aseg(kglob, seg, stride, off);
      int kloc = off + khi;
#pragma unroll
      for (int mb = 0; mb < 4; ++mb)
        aN[mb] = *(const uint4*)(seg + (long)(mb * 16 + rlo) * stride + kloc);
      bN = *(const uint4*)(PW + (((long)(kglob >> 5) * 256 + nblk) * 64 + lane) * 8);
    }
    s16x8 b = __builtin_bit_cast(s16x8, bC);
#pragma unroll
    for (int mb = 0; mb < 4; ++mb)
      acc[mb] = __builtin_amdgcn_mfma_f32_16x16x32_bf16(
          __builtin_bit_cast(s16x8, aC[mb]), b, acc[mb], 0, 0, 0);
  }
  float* Pout = (att ? P.Patt : P.Pdec) + (long)kc * 64 * G4A;
  int col = nblk * 16 + rlo;
  int rbase = (lane >> 4) * 4;
#pragma unroll
  for (int mb = 0; mb < 4; ++mb)
#pragma unroll
    for (int r = 0; r < 4; ++r)
      Pout[(long)(mb * 16 + rbase + r) * G4A + col] = acc[mb][r];
}

// att LSTM pointwise(t) for batch b + GMM + alpha (no ctx)
__device__ __forceinline__ void dev_attpw(const Ptrs& P, int t, int b,
    float* ah_s, float* red_s, float* tanh_s, float* bc_s) {
  int tid = threadIdx.x;
  int bf = *P.flag;
  for (int u = tid; u < 1024; u += 256) {
    float gi = P.bai[u]        + P.bah[u];
    float gf = P.bai[u + 1024] + P.bah[u + 1024];
    float gg = P.bai[u + 2048] + P.bah[u + 2048];
    float go = P.bai[u + 3072] + P.bah[u + 3072];
    for (int kc = 0; kc < ACH; ++kc) {
      const float* pa = P.Patt + ((long)kc * 64 + b) * G4A;
      gi += pa[u]; gf += pa[u + 1024]; gg += pa[u + 2048]; go += pa[u + 3072];
    }
    float ii = sigm(gi), ff = sigm(gf), oo = sigm(go);
    float cc = ff * P.ac[b * 1024 + u] + ii * tanhf(gg);
    float hh = oo * tanhf(cc);
    P.ac[b * 1024 + u] = cc;
    P.ah[b * 1024 + u] = hh;
    P.ah_bf[b * 1024 + u] = f2bf(hh);
    ah_s[u] = hh;
  }
  __syncthreads();
  {
    int g = tid & 127, hf = tid >> 7;
    const float* w = P.Wg1 + g;
    float a0 = 0.f, a1 = 0.f;
    int u0 = hf * 512;
    for (int u = u0; u < u0 + 512; u += 2) {
      a0 += ah_s[u]     * w[(long)u * 128];
      a1 += ah_s[u + 1] * w[(long)(u + 1) * 128];
    }
    red_s[tid] = a0 + a1;
  }
  __syncthreads();
  if (tid < 128) tanh_s[tid] = tanhf(red_s[tid] + red_s[tid + 128] + P.bg1[tid]);
  __syncthreads();
  if (tid < 64) {
    float tv0 = tanh_s[tid], tv1 = tanh_s[tid + 64];
    float h0 = tv0 * P.Wg2[2 * tid]     + tv1 * P.Wg2[2 * (tid + 64)];
    float h1 = tv0 * P.Wg2[2 * tid + 1] + tv1 * P.Wg2[2 * (tid + 64) + 1];
#pragma unroll
    for (int o = 32; o; o >>= 1) { h0 += __shfl_down(h0, o); h1 += __shfl_down(h1, o); }
    if (tid == 0) {
      float m  = P.mean[b] + expf(h0) * 8.f;
      float sc = expf(h1) * 8.f;
      P.mean[b] = m;
      long pidx = PARAMS_OFF + ((long)b * Tn + t) * 2;
      store_out(P.out, pidx, h0, bf);
      store_out(P.out, pidx + 1, h1, bf);
      bc_s[0] = m; bc_s[1] = sc;
    }
  }
  __syncthreads();
  float m = bc_s[0], sc = bc_s[1];
  int len = P.mlen[b];
  int ci = (int)floorf(fminf(m, 100000.f));
  int l0 = ci - 80; if (l0 < 0) l0 = 0;
  int l1 = ci + 81; if (l1 > len) l1 = len;
  float inv2 = 0.5f / (sc * sc);
  float invZ = 1.f / (2.50662827463100050242f * sc);
  for (int l = l0 + tid; l < l1; l += 256) {
    float d = (float)l - m;
    float al = expf(-d * d * inv2) * invZ;
    P.alpha_ws[b * 176 + (l - l0)] = al;
    store_out(P.out, ALIGNS_OFF + ((long)b * Tn + t) * Ln + l, al, bf);
  }
  if (tid == 0) { P.lws[2 * b] = l0; P.lws[2 * b + 1] = l1 - l0; }
  __syncthreads();
}

// dec LSTM pointwise(t-1), 2 batch rows per task
template<typename ST>
__device__ __forceinline__ void dev_decpw(const Ptrs& P, int t, int bb) {
  int tid = threadIdx.x;
  ST* dh_all = (ST*)P.dh_all;
  for (int i = tid; i < 2048; i += 256) {
    int b = bb * 2 + (i >> 10), u = i & 1023;
    float gi = P.bdi[u]        + P.bdh[u];
    float gf = P.bdi[u + 1024] + P.bdh[u + 1024];
    float gg = P.bdi[u + 2048] + P.bdh[u + 2048];
    float go = P.bdi[u + 3072] + P.bdh[u + 3072];
    for (int kc = 0; kc < DCH; ++kc) {
      const float* pd = P.Pdec + ((long)kc * 64 + b) * G4A;
      gi += pd[u]; gf += pd[u + 1024]; gg += pd[u + 2048]; go += pd[u + 3072];
    }
    float ii = sigm(gi), ff = sigm(gf), oo = sigm(go);
    float cc = ff * P.dc[b * 1024 + u] + ii * tanhf(gg);
    float hh = oo * tanhf(cc);
    P.dc[b * 1024 + u] = cc;
    P.dh[b * 1024 + u] = hh;
    P.dh_bf[b * 1024 + u] = f2bf(hh);
    st_store(dh_all, ((long)(t - 1) * 64 + b) * 1024 + u, hh);
  }
}

// ctx gather for (b, e-half): 256 e per task, 1 e per thread
template<typename ST>
__device__ __forceinline__ void dev_ctx(const Ptrs& P, int t, int b, int half, float* alpha_s) {
  int tid = threadIdx.x;
  int bf = *P.flag;
  int l0 = P.lws[2 * b], nl = P.lws[2 * b + 1];
  for (int i = tid; i < nl; i += 256) alpha_s[i] = P.alpha_ws[b * 176 + i];
  __syncthreads();
  int e = half * 256 + tid;
  float s = 0.f;
  if (bf) {
    const unsigned short* mem = (const unsigned short*)P.mem + ((long)b * Ln + l0) * En + e;
    for (int l = 0; l < nl; ++l) s += alpha_s[l] * ldbf(mem, (long)l * En);
  } else {
    const float* mem = (const float*)P.mem + ((long)b * Ln + l0) * En + e;
    for (int l = 0; l < nl; ++l) s += alpha_s[l] * mem[(long)l * En];
  }
  P.ctx[b * En + e] = s;
  P.ctx_bf[b * En + e] = f2bf(s);
  st_store((ST*)P.ctx_all, ((long)t * 64 + b) * En + e, s);
  __syncthreads();
}

// ---------------- the persistent decoder loop ----------------
template<typename ST>
__global__ __launch_bounds__(256, 2) void k_persist(Ptrs P, int* bar) {
  __shared__ float ah_s[1024];
  __shared__ float red_s[256];
  __shared__ float tanh_s[128];
  __shared__ float bc_s[2];
  __shared__ float alpha_s[176];
  int nb = (int)gridDim.x, bid = (int)blockIdx.x;
  int* cnt = bar;
  int* gen = bar + 32;
  for (int t = -1; t <= Tn; ++t) {
    // P1: att pointwise(t) + GMM + alpha | dec pointwise(t-1)
    if (t >= 0) {
      for (int vb = bid; vb < 96; vb += nb) {
        if (vb < 64) { if (t < Tn) dev_attpw(P, t, vb, ah_s, red_s, tanh_s, bc_s); }
        else if (t >= 1) dev_decpw<ST>(P, t, vb - 64);
      }
    }
    gsync(cnt, gen);
    // P2: ctx(t)
    if (t >= 0 && t < Tn) {
      for (int vb = bid; vb < 128; vb += nb)
        dev_ctx<ST>(P, t, vb >> 1, vb & 1, alpha_s);
    }
    gsync(cnt, gen);
    // P3: att gates(t+1) + dec gates(t)
    for (int vb = bid; vb < 512; vb += nb) dev_gemm(P, t, vb);
    gsync(cnt, gen);
  }
}

// ---------------- final projection: logits = [dh, ctx] @ W_proj + b ----------------
template<typename ST>
__global__ __launch_bounds__(256) void k_proj(Ptrs P) {
  __shared__ __align__(16) float A_s[64][65];
  __shared__ __align__(16) float W_s[64 * 160];
  int t = blockIdx.x, tid = threadIdx.x;
  int bf = *P.flag;
  const ST* dh_all = (const ST*)P.dh_all;
  const ST* ctx_all = (const ST*)P.ctx_all;
  int tc = tid & 15, tr = tid >> 4;
  int c0 = tc * 10, b0 = tr * 4;
  float acc[4][10];
#pragma unroll
  for (int i = 0; i < 4; ++i)
#pragma unroll
    for (int j = 0; j < 10; ++j) acc[i][j] = 0.f;
  for (int k0 = 0; k0 < KPROJ; k0 += 64) {
    __syncthreads();
    for (int i = tid; i < 64 * 64; i += 256) {
      int b = i >> 6, kk = i & 63;
      int k = k0 + kk;
      float v = (k < Dn) ? st_load(dh_all, ((long)t * 64 + b) * Dn + k)
                         : st_load(ctx_all, ((long)t * 64 + b) * En + (k - Dn));
      A_s[b][kk] = v;
    }
    for (int i = tid; i < 64 * 160; i += 256) {
      int kk = i / 160, c = i - kk * 160;
      W_s[kk * 160 + c] = (c < Vn) ? P.Wpr[(long)(k0 + kk) * Vn + c] : 0.f;
    }
    __syncthreads();
    for (int kk = 0; kk < 64; ++kk) {
      float xs[4];
#pragma unroll
      for (int i = 0; i < 4; ++i) xs[i] = A_s[b0 + i][kk];
#pragma unroll
      for (int j = 0; j < 10; ++j) {
        float w = W_s[kk * 160 + c0 + j];
#pragma unroll
        for (int i = 0; i < 4; ++i) acc[i][j] += xs[i] * w;
      }
    }
  }
#pragma unroll
  for (int i = 0; i < 4; ++i)
#pragma unroll
    for (int j = 0; j < 10; ++j) {
      int c = c0 + j;
      if (c < Vn) {
        int b = b0 + i;
        store_out(P.out, LOGITS_OFF + ((long)b * Tn + t) * Vn + c, acc[i][j] + P.bpr[c], bf);
      }
    }
}

// ---------------- host ----------------
template<typename ST>
static void run_pipeline(const Ptrs& P, int* bar, hipStream_t stream) {
  k_prenet<<<Tn * 2, 256, 0, stream>>>(P, DK1.a, DK1.b, DK2.a, DK2.b);
  int cus = 0, occ = 0;
  if (hipDeviceGetAttribute(&cus, hipDeviceAttributeMultiprocessorCount, 0) != hipSuccess || cus <= 0)
    cus = 256;
  if (hipOccupancyMaxActiveBlocksPerMultiprocessor(&occ, k_persist<ST>, 256, 0) != hipSuccess || occ < 1)
    occ = 1;
  int grid = occ * cus;
  if (grid > 512) grid = 512;
  k_persist<ST><<<grid, 256, 0, stream>>>(P, bar);
  k_proj<ST><<<Tn, 256, 0, stream>>>(P);
}

extern "C" void kernel_launch(void* const* d_in, const int* in_sizes, int n_in,
                              void* d_out, int out_size, void* d_ws, size_t ws_size,
                              hipStream_t stream) {
  (void)in_sizes; (void)n_in; (void)out_size;
  char* base = (char*)d_ws;
  int* flag = (int*)base;
  size_t off = 256;
  auto allocf = [&](size_t n) -> float* {
    float* p = (float*)(base + off);
    off += ((n * 4 + 255) / 256) * 256;
    return p;
  };
  auto allocu = [&](size_t n) -> unsigned short* {
    unsigned short* p = (unsigned short*)(base + off);
    off += ((n * 2 + 255) / 256) * 256;
    return p;
  };
  int* bar = (int*)(base + off); off += 256;          // [cnt, pad, gen, pad]
  float* Wp1 = allocf(131072);
  float* Wp2 = allocf(65536);
  float* bai = allocf(4096);
  float* bah = allocf(4096);
  float* Wg1 = allocf(131072);
  float* bg1 = allocf(128);
  float* Wg2 = allocf(256);
  float* bdi = allocf(4096);
  float* bdh = allocf(4096);
  float* Wpr = allocf(227328);
  float* bpr = allocf(148);
  unsigned short* PWatt = allocu((size_t)NKB_ATT * 256 * 512);  // bf16 packed
  unsigned short* PWdec = allocu((size_t)NKB_DEC * 256 * 512);
  unsigned short* pre_bf = allocu((size_t)Tn * 64 * Pn);
  float* Patt = allocf((size_t)ACH * 64 * G4A);
  float* Pdec = allocf((size_t)DCH * 64 * G4A);
  float* ah = allocf(65536);
  float* ac = allocf(65536);
  float* dh = allocf(65536);
  float* dc = allocf(65536);
  float* ctx = allocf(32768);
  float* mean = allocf(64);
  unsigned short* ah_bf = allocu(65536);
  unsigned short* ctx_bf = allocu(32768);
  unsigned short* dh_bf = allocu(65536);
  float* alpha_ws = allocf(64 * 176);
  int* lws = (int*)allocf(128);
  size_t fixed = off;
  size_t nDH = (size_t)Tn * 64 * Dn, nCX = (size_t)Tn * 64 * En;
  bool f32tier = (fixed + (nDH + nCX) * 4 <= ws_size);
  bool b16tier = (fixed + (nDH + nCX) * 2 <= ws_size);
  if (!f32tier && !b16tier) return;

  Ptrs P;
  P.Wp1=Wp1; P.Wp2=Wp2; P.bai=bai; P.bah=bah; P.Wg1=Wg1; P.bg1=bg1; P.Wg2=Wg2;
  P.bdi=bdi; P.bdh=bdh; P.Wpr=Wpr; P.bpr=bpr;
  P.PWatt=PWatt; P.PWdec=PWdec; P.pre_bf=pre_bf;
  P.ah_bf=ah_bf; P.ctx_bf=ctx_bf; P.dh_bf=dh_bf;
  P.Patt=Patt; P.Pdec=Pdec; P.ah=ah; P.ac=ac; P.dh=dh; P.dc=dc;
  P.ctx=ctx; P.mean=mean; P.alpha_ws=alpha_ws; P.lws=lws;
  size_t esz = f32tier ? 4 : 2;
  P.dh_all  = base + fixed;
  P.ctx_all = base + fixed + nDH * esz;
  P.mem = d_in[0]; P.din = d_in[1]; P.mlen = (const int*)d_in[2];
  P.w_ai = d_in[5]; P.w_ah = d_in[6]; P.w_di = d_in[12]; P.w_dh = d_in[13];
  P.flag = flag; P.out = d_out;

  k_detect<<<1, 256, 0, stream>>>(d_in[0], flag);

  struct CV { const void* s; float* d; long n; };
  const CV cv[11] = {
    {d_in[3], Wp1, 131072}, {d_in[4], Wp2, 65536},
    {d_in[7], bai, 4096}, {d_in[8], bah, 4096},
    {d_in[9], Wg1, 131072}, {d_in[10], bg1, 128}, {d_in[11], Wg2, 256},
    {d_in[14], bdi, 4096}, {d_in[15], bdh, 4096},
    {d_in[16], Wpr, 227328}, {d_in[17], bpr, 148},
  };
  for (int i = 0; i < 11; ++i) {
    long g = (cv[i].n + 255) / 256; if (g > 1024) g = 1024;
    k_convert<<<(int)g, 256, 0, stream>>>(cv[i].s, cv[i].d, cv[i].n, flag);
  }
  k_pack<<<(NKB_ATT + NKB_DEC) * 64, 256, 0, stream>>>(P);
  // zero barrier + fp32 states + bf16 mirrors (contiguous from ah)
  k_zero_f32<<<1, 64, 0, stream>>>((float*)bar, 64);
  k_zero_f32<<<512, 256, 0, stream>>>(ah, 294976 + 81920);
  k_zero_aligns<<<2048, 256, 0, stream>>>(d_out, flag);

  if (f32tier) run_pipeline<float>(P, bar, stream);
  else         run_pipeline<unsigned short>(P, bar, stream);
}

// Round 5
// 64098.730 us; speedup vs baseline: 2.4140x; 2.4140x over previous
//
#include <hip/hip_runtime.h>
#include <math.h>

// ---------------- config ----------------
#define TF_PARTITIONABLE 1   // jax threefry_partitionable (default True since jax 0.4.36)

static constexpr int Bn=64, Ln=512, En=512, Tn=512, Sn=512, Pn=256, An=1024, Dn=1024, Gn=128, Vn=148;
static constexpr int G4A = 4096;            // 4*A == 4*D
static constexpr int KPROJ = Dn + En;       // 1536
static constexpr int KATT = 1792, KDEC = 2560;
static constexpr int ACH = 4, ACK = 448;    // att gates K = 4 chunks x 448 (NK=14)
static constexpr int DCH = 4, DCK = 640;    // dec gates K = 4 chunks x 640 (NK=20)
static constexpr int NKB_ATT = KATT / 32;   // 56 k-blocks
static constexpr int NKB_DEC = KDEC / 32;   // 80
static constexpr long LOGITS_OFF = 0;
static constexpr long ALIGNS_OFF = (long)Bn*Tn*Vn;               // 4,849,664
static constexpr long PARAMS_OFF = ALIGNS_OFF + (long)Bn*Tn*Ln;  // 21,626,880

using s16x8 = __attribute__((ext_vector_type(8))) short;
using f32x4 = __attribute__((ext_vector_type(4))) float;

// ---------------- threefry2x32 (jax-exact) ----------------
struct TFo { unsigned a, b; };
static constexpr TFo htf(unsigned k1, unsigned k2, unsigned x0, unsigned x1) {
  unsigned ks2 = k1 ^ k2 ^ 0x1BD11BDAu;
  unsigned ks[3] = {k1, k2, ks2};
  const unsigned ra[4] = {13u,15u,26u,6u}, rb[4] = {17u,29u,16u,24u};
  x0 += k1; x1 += k2;
  for (int g = 0; g < 5; ++g) {
    const unsigned* r = (g % 2 == 0) ? ra : rb;
    for (int i = 0; i < 4; ++i) { x0 += x1; x1 = (x1 << r[i]) | (x1 >> (32u - r[i])); x1 ^= x0; }
    x0 += ks[(g+1)%3]; x1 += ks[(g+2)%3] + (unsigned)(g+1);
  }
  return TFo{x0, x1};
}
#if TF_PARTITIONABLE
static constexpr TFo DK1 = htf(0u,42u,0u,0u);
static constexpr TFo DK2 = htf(0u,42u,0u,1u);
#else
static constexpr TFo S02 = htf(0u,42u,0u,2u);
static constexpr TFo S13 = htf(0u,42u,1u,3u);
static constexpr TFo DK1 = TFo{S02.a, S13.a};
static constexpr TFo DK2 = TFo{S02.b, S13.b};
#endif

__device__ __forceinline__ void dtf(unsigned k1, unsigned k2, unsigned x0, unsigned x1,
                                    unsigned& o0, unsigned& o1) {
  unsigned ks2 = k1 ^ k2 ^ 0x1BD11BDAu;
#define TFR(r) { x0 += x1; x1 = (x1<<r)|(x1>>(32-r)); x1 ^= x0; }
  x0 += k1; x1 += k2;
  TFR(13) TFR(15) TFR(26) TFR(6)  x0 += k2;  x1 += ks2 + 1u;
  TFR(17) TFR(29) TFR(16) TFR(24) x0 += ks2; x1 += k1 + 2u;
  TFR(13) TFR(15) TFR(26) TFR(6)  x0 += k1;  x1 += k2 + 3u;
  TFR(17) TFR(29) TFR(16) TFR(24) x0 += k2;  x1 += ks2 + 4u;
  TFR(13) TFR(15) TFR(26) TFR(6)  x0 += ks2; x1 += k1 + 5u;
#undef TFR
  o0 = x0; o1 = x1;
}

__device__ __forceinline__ bool keepmask(unsigned ka, unsigned kb, unsigned j) {
#if TF_PARTITIONABLE
  unsigned o0, o1; dtf(ka, kb, 0u, j, o0, o1);
  return ((o0 ^ o1) >> 31) == 0u;
#else
  const unsigned H = 4202496u;  // (513*64*256)/2
  unsigned o0, o1;
  if (j < H) { dtf(ka, kb, j, j + H, o0, o1); return (o0 >> 31) == 0u; }
  else       { dtf(ka, kb, j - H, j, o0, o1); return (o1 >> 31) == 0u; }
#endif
}

// ---------------- dtype helpers ----------------
__device__ __forceinline__ float ldbf(const unsigned short* p, long i) {
  return __uint_as_float(((unsigned)p[i]) << 16);
}
__device__ __forceinline__ unsigned short f2bf(float v) {
  unsigned x = __float_as_uint(v);
  return (unsigned short)((x + 0x7fffu + ((x >> 16) & 1u)) >> 16);  // RNE
}
__device__ __forceinline__ void store_out(void* out, long i, float v, int bf) {
  if (bf) ((unsigned short*)out)[i] = f2bf(v);
  else    ((float*)out)[i] = v;
}
__device__ __forceinline__ float st_load(const float* p, long i) { return p[i]; }
__device__ __forceinline__ float st_load(const unsigned short* p, long i) { return ldbf(p, i); }
__device__ __forceinline__ void st_store(float* p, long i, float v) { p[i] = v; }
__device__ __forceinline__ void st_store(unsigned short* p, long i, float v) { p[i] = f2bf(v); }
__device__ __forceinline__ float sigm(float x) { return 1.f / (1.f + expf(-x)); }

// ---- L2-bypassing (device-coherent) accessors: relaxed agent-scope atomics ----
// These compile to global_load/store with sc1 (no cache maintenance, no fences).
__device__ __forceinline__ unsigned long long ldq_byp(const void* p) {
  return __hip_atomic_load((const unsigned long long*)p, __ATOMIC_RELAXED, __HIP_MEMORY_SCOPE_AGENT);
}
__device__ __forceinline__ void stq_byp(void* p, unsigned long long v) {
  __hip_atomic_store((unsigned long long*)p, v, __ATOMIC_RELAXED, __HIP_MEMORY_SCOPE_AGENT);
}
__device__ __forceinline__ s16x8 lda8(const unsigned short* p) {   // 8 bf16 (16B) via 2 u64
  union { unsigned long long q[2]; s16x8 v; } u;
  u.q[0] = ldq_byp(p); u.q[1] = ldq_byp(p + 4);
  return u.v;
}
__device__ __forceinline__ float4 ldf4_byp(const float* p) {       // 4 f32 via 2 u64
  union { unsigned long long q[2]; float4 f; } u;
  u.q[0] = ldq_byp(p); u.q[1] = ldq_byp(p + 2);
  return u.f;
}
__device__ __forceinline__ void st4_bf_byp(unsigned short* p, float a, float b, float c, float d) {
  unsigned long long q = (unsigned long long)f2bf(a) | ((unsigned long long)f2bf(b) << 16)
                       | ((unsigned long long)f2bf(c) << 32) | ((unsigned long long)f2bf(d) << 48);
  stq_byp(p, q);
}
__device__ __forceinline__ void stf_byp(float* p, float v) {
  __hip_atomic_store(p, v, __ATOMIC_RELAXED, __HIP_MEMORY_SCOPE_AGENT);
}

// ---------------- pointer pack ----------------
struct Ptrs {
  const float *Wp1,*Wp2,*bai,*bah,*Wg1,*bg1,*Wg2,*bdi,*bdh,*Wpr,*bpr;
  unsigned short *PWatt,*PWdec,*pre_bf,*ah_bf,*ctx_bf,*dh_bf;
  float *Patt,*Pdec,*ac,*dc,*mean;
  void *dh_all,*ctx_all;
  const void *mem,*din,*w_ai,*w_ah,*w_di,*w_dh;
  const int *mlen; const int *flag; void *out;
};

// ---------------- grid barrier: striped relaxed atomics, monotonic epochs ----------------
// bar layout (ints): [0..511] 16 group counters at stride 32; [512] master; [544] gen.
// No fences anywhere: all cross-block data moves via sc1 accessors above; the
// pre-barrier __syncthreads() drains each thread's vmcnt (stores at coherent point).
__device__ __forceinline__ void gsync(int* bar, int epoch) {
  __syncthreads();
  if (threadIdx.x == 0) {
    int* gc = bar + ((int)blockIdx.x & 15) * 32;
    int* mc = bar + 512;
    int* gv = bar + 544;
    int v = __hip_atomic_fetch_add(gc, 1, __ATOMIC_RELAXED, __HIP_MEMORY_SCOPE_AGENT) + 1;
    if (v == 32 * epoch) {   // last arrival of this group for this epoch
      int m = __hip_atomic_fetch_add(mc, 1, __ATOMIC_RELAXED, __HIP_MEMORY_SCOPE_AGENT) + 1;
      if (m == 16 * epoch)
        __hip_atomic_store(gv, epoch, __ATOMIC_RELAXED, __HIP_MEMORY_SCOPE_AGENT);
    }
    long long t0 = clock64();
    while (__hip_atomic_load(gv, __ATOMIC_RELAXED, __HIP_MEMORY_SCOPE_AGENT) < epoch) {
      __builtin_amdgcn_s_sleep(16);
      if (clock64() - t0 > (1LL << 31)) break;  // escape hatch: fail visibly, never hang
    }
  }
  __syncthreads();
}

// ---------------- utility kernels ----------------
__global__ __launch_bounds__(256) void k_detect(const void* mem, int* flag) {
  __shared__ int cnt;
  int tid = threadIdx.x;
  if (tid == 0) cnt = 0;
  __syncthreads();
  const unsigned short* p = (const unsigned short*)mem;
  int local = 0;
  for (int i = tid; i < 1024; i += 256) {
    float f = ldbf(p, 2L * i);
    if (f == f && fabsf(f) > 0.0009f && fabsf(f) < 16.f) local++;
  }
  atomicAdd(&cnt, local);
  __syncthreads();
  if (tid == 0) flag[0] = (cnt > 512) ? 1 : 0;
}

__global__ __launch_bounds__(256) void k_convert(const void* src, float* dst, long n, const int* flag) {
  int bf = *flag;
  long i0 = (long)blockIdx.x * 256 + threadIdx.x, stp = (long)gridDim.x * 256;
  if (bf) { const unsigned short* s = (const unsigned short*)src;
            for (long i = i0; i < n; i += stp) dst[i] = ldbf(s, i); }
  else    { const float* s = (const float*)src;
            for (long i = i0; i < n; i += stp) dst[i] = s[i]; }
}

__global__ __launch_bounds__(256) void k_zero_f32(float* p, long n) {
  for (long i = (long)blockIdx.x * 256 + threadIdx.x; i < n; i += (long)gridDim.x * 256) p[i] = 0.f;
}

__global__ __launch_bounds__(256) void k_zero_aligns(void* out, const int* flag) {
  int bf = *flag;
  unsigned* p; long n;
  if (bf) { p = (unsigned*)out + (ALIGNS_OFF >> 1); n = ((long)Bn*Tn*Ln) >> 1; }
  else    { p = (unsigned*)out + ALIGNS_OFF;        n = (long)Bn*Tn*Ln; }
  for (long i = (long)blockIdx.x * 256 + threadIdx.x; i < n; i += (long)gridDim.x * 256) p[i] = 0u;
}

// ---------------- weight packing: bf16 B-fragment order ----------------
// PW[kblk][nblk][lane][8]: lane l elem j <-> W[kblk*32 + (l>>4)*8 + j][nblk*16 + (l&15)]
__global__ __launch_bounds__(256) void k_pack(Ptrs P) {
  __shared__ float s[32][65];
  int bid = blockIdx.x, tid = threadIdx.x;
  bool att = bid < NKB_ATT * 64;
  int lb = att ? bid : bid - NKB_ATT * 64;
  int kblk = lb >> 6, ng = lb & 63;
  int n0 = ng * 64;
  int bf = *P.flag;
  int split = att ? (Pn + En) : (An + En);
  const void* S0 = att ? P.w_ai : P.w_di;
  const void* S1 = att ? P.w_ah : P.w_dh;
  for (int i = tid; i < 2048; i += 256) {
    int kk = i >> 6, n = i & 63;
    int k = kblk * 32 + kk;
    const void* src = (k < split) ? S0 : S1;
    long idx = (long)(k < split ? k : k - split) * G4A + (n0 + n);
    s[kk][n] = bf ? ldbf((const unsigned short*)src, idx) : ((const float*)src)[idx];
  }
  __syncthreads();
  int lane = tid & 63, tb = tid >> 6;
  unsigned short r[8];
#pragma unroll
  for (int j = 0; j < 8; ++j)
    r[j] = f2bf(s[(lane >> 4) * 8 + j][tb * 16 + (lane & 15)]);
  unsigned short* out = (att ? P.PWatt : P.PWdec) +
      (((long)kblk * 256 + (ng * 4 + tb)) * 64 + lane) * 8;
  *(uint4*)out = *(const uint4*)r;
}

// ---------------- prenet (fused GEMM1+mask1+GEMM2+mask2) -> bf16 ----------------
__global__ __launch_bounds__(256) void k_prenet(Ptrs P, unsigned k1a, unsigned k1b,
                                                unsigned k2a, unsigned k2b) {
  __shared__ __align__(16) float x_s[32 * 17];
  __shared__ __align__(16) float W_s[16 * 256];
  __shared__ __align__(16) float h1_s[32 * 258];
  int bid = blockIdx.x, tid = threadIdx.x;
  int t = bid >> 1, half = bid & 1;
  int bf = *P.flag;
  int tc = tid & 63, tr = tid >> 6;
  int p0 = tc * 4, bl0 = tr * 8;
  float acc[8][4];
#pragma unroll
  for (int i = 0; i < 8; ++i) { acc[i][0]=0; acc[i][1]=0; acc[i][2]=0; acc[i][3]=0; }

  for (int kc = 0; kc < 32; ++kc) {
    __syncthreads();
    for (int i = tid; i < 32 * 16; i += 256) {
      int bl = i >> 4, kk = i & 15;
      int s = kc * 16 + kk;
      float v = 0.f;
      if (t > 0) {
        long idx = ((long)(half * 32 + bl) * Sn + s) * Tn + (t - 1);
        v = bf ? ldbf((const unsigned short*)P.din, idx) : ((const float*)P.din)[idx];
      }
      x_s[bl * 17 + kk] = v;
    }
    for (int i = tid; i < 16 * 256; i += 256) {
      int kk = i >> 8, p = i & 255;
      W_s[kk * 256 + p] = P.Wp1[(long)(kc * 16 + kk) * 256 + p];
    }
    __syncthreads();
    for (int kk = 0; kk < 16; ++kk) {
      float4 w = *(const float4*)(W_s + kk * 256 + p0);
#pragma unroll
      for (int i = 0; i < 8; ++i) {
        float x = x_s[(bl0 + i) * 17 + kk];
        acc[i][0] += x * w.x; acc[i][1] += x * w.y; acc[i][2] += x * w.z; acc[i][3] += x * w.w;
      }
    }
  }
#pragma unroll
  for (int i = 0; i < 8; ++i)
#pragma unroll
    for (int j = 0; j < 4; ++j) {
      int bl = bl0 + i, p = p0 + j, bg = half * 32 + bl;
      float v = fmaxf(acc[i][j], 0.f);
      unsigned ft = (unsigned)(((long)t * 64 + bg) * 256 + p);
      v = keepmask(k1a, k1b, ft) ? 2.f * v : 0.f;
      h1_s[bl * 258 + p] = v;
      acc[i][j] = 0.f;
    }
  __syncthreads();
  for (int kc = 0; kc < 16; ++kc) {
    __syncthreads();
    for (int i = tid; i < 16 * 256; i += 256) {
      int kk = i >> 8, p = i & 255;
      W_s[kk * 256 + p] = P.Wp2[(long)(kc * 16 + kk) * 256 + p];
    }
    __syncthreads();
    for (int kk = 0; kk < 16; ++kk) {
      float4 w = *(const float4*)(W_s + kk * 256 + p0);
      int s = kc * 16 + kk;
#pragma unroll
      for (int i = 0; i < 8; ++i) {
        float x = h1_s[(bl0 + i) * 258 + s];
        acc[i][0] += x * w.x; acc[i][1] += x * w.y; acc[i][2] += x * w.z; acc[i][3] += x * w.w;
      }
    }
  }
#pragma unroll
  for (int i = 0; i < 8; ++i)
#pragma unroll
    for (int j = 0; j < 4; ++j) {
      int bg = half * 32 + bl0 + i, p = p0 + j;
      float v = fmaxf(acc[i][j], 0.f);
      unsigned ft = (unsigned)(((long)t * 64 + bg) * 256 + p);
      v = keepmask(k2a, k2b, ft) ? 2.f * v : 0.f;
      P.pre_bf[((long)t * 64 + bg) * 256 + p] = f2bf(v);
    }
}

// ---------------- device phase bodies ----------------
// gate GEMM: A via bypass loads (cross-XCD fresh), B(weights) cached (L2-resident).
template<bool ATT, int NK>
__device__ __forceinline__ void dev_gemm_t(const Ptrs& P, int t, int lb) {
  int tid = threadIdx.x;
  int nb4 = lb >> 2, kc = lb & 3;
  int lane = tid & 63, w = tid >> 6;
  int nblk = nb4 * 4 + w;
  const int CK = ATT ? ACK : DCK;
  const int k0 = kc * CK;
  const unsigned short* PW = ATT ? P.PWatt : P.PWdec;
  const unsigned short* pre_t = P.pre_bf + (long)(t + 1) * 64 * Pn;
  int rlo = lane & 15, khi = (lane >> 4) * 8;

  auto aptr = [&](int kglob, int mb) -> const unsigned short* {
    const unsigned short* seg; int stride; int off;
    if (ATT) {
      if (kglob < Pn)           { seg = pre_t;    stride = Pn; off = kglob; }
      else if (kglob < Pn + En) { seg = P.ctx_bf; stride = En; off = kglob - Pn; }
      else                      { seg = P.ah_bf;  stride = An; off = kglob - Pn - En; }
    } else {
      if (kglob < An)           { seg = P.ah_bf;  stride = An; off = kglob; }
      else if (kglob < An + En) { seg = P.ctx_bf; stride = En; off = kglob - An; }
      else                      { seg = P.dh_bf;  stride = Dn; off = kglob - An - En; }
    }
    return seg + (long)(mb * 16 + rlo) * stride + off + khi;
  };

  f32x4 acc[4];
#pragma unroll
  for (int i = 0; i < 4; ++i) acc[i] = f32x4{0.f, 0.f, 0.f, 0.f};
  s16x8 ab[2][4], bb[2];
#pragma unroll
  for (int mb = 0; mb < 4; ++mb) ab[0][mb] = lda8(aptr(k0, mb));
  bb[0] = *(const s16x8*)(PW + (((long)(k0 >> 5) * 256 + nblk) * 64 + lane) * 8);
#pragma unroll
  for (int kk = 0; kk < NK; ++kk) {
    const int cur = kk & 1, nxt = cur ^ 1;
    if (kk + 1 < NK) {
      int kg = k0 + (kk + 1) * 32;
#pragma unroll
      for (int mb = 0; mb < 4; ++mb) ab[nxt][mb] = lda8(aptr(kg, mb));
      bb[nxt] = *(const s16x8*)(PW + (((long)(kg >> 5) * 256 + nblk) * 64 + lane) * 8);
    }
#pragma unroll
    for (int mb = 0; mb < 4; ++mb)
      acc[mb] = __builtin_amdgcn_mfma_f32_16x16x32_bf16(ab[cur][mb], bb[cur], acc[mb], 0, 0, 0);
  }
  float* Pout = (ATT ? P.Patt : P.Pdec) + (long)kc * 64 * G4A;
  int col = nblk * 16 + rlo, rbase = (lane >> 4) * 4;
#pragma unroll
  for (int mb = 0; mb < 4; ++mb)
#pragma unroll
    for (int r = 0; r < 4; ++r)
      stf_byp(&Pout[(long)(mb * 16 + rbase + r) * G4A + col], acc[mb][r]);
}

__device__ __forceinline__ void dev_gemm(const Ptrs& P, int t, int vb) {
  if (vb < 256) { if (t + 1 < Tn) dev_gemm_t<true,  ACK/32>(P, t, vb); }
  else          { if (t >= 0 && t < Tn) dev_gemm_t<false, DCK/32>(P, t, vb - 256); }
}

// att LSTM pointwise(t) + GMM + alpha + ctx for batch b (all block-local except mirrors)
template<typename ST>
__device__ __forceinline__ void dev_attpw(const Ptrs& P, int t, int b,
    float* ah_s, float* red_s, float* tanh_s, float* bc_s, float* alpha_s) {
  int tid = threadIdx.x;
  int bf = *P.flag;
  int u0 = tid * 4;
  float gv[4][4];
#pragma unroll
  for (int gt = 0; gt < 4; ++gt) {
    float4 a = *(const float4*)(P.bai + gt * 1024 + u0);
    float4 c = *(const float4*)(P.bah + gt * 1024 + u0);
    gv[gt][0] = a.x + c.x; gv[gt][1] = a.y + c.y; gv[gt][2] = a.z + c.z; gv[gt][3] = a.w + c.w;
  }
#pragma unroll
  for (int kc = 0; kc < ACH; ++kc) {
    const float* pa = P.Patt + ((long)kc * 64 + b) * G4A + u0;
#pragma unroll
    for (int gt = 0; gt < 4; ++gt) {
      float4 v = ldf4_byp(pa + gt * 1024);
      gv[gt][0] += v.x; gv[gt][1] += v.y; gv[gt][2] += v.z; gv[gt][3] += v.w;
    }
  }
  float4 oc = *(const float4*)(P.ac + b * 1024 + u0);
  float oldc[4] = {oc.x, oc.y, oc.z, oc.w};
  float hh[4], cc[4];
#pragma unroll
  for (int i = 0; i < 4; ++i) {
    float ii = sigm(gv[0][i]), ff = sigm(gv[1][i]), oo = sigm(gv[3][i]);
    cc[i] = ff * oldc[i] + ii * tanhf(gv[2][i]);
    hh[i] = oo * tanhf(cc[i]);
    ah_s[u0 + i] = hh[i];
  }
  *(float4*)(P.ac + b * 1024 + u0) = make_float4(cc[0], cc[1], cc[2], cc[3]);
  st4_bf_byp(P.ah_bf + b * 1024 + u0, hh[0], hh[1], hh[2], hh[3]);
  __syncthreads();
  // GMM hidden: tanh(ah @ W_g1 + b_g1)
  {
    int g = tid & 127, hf = tid >> 7;
    const float* wg = P.Wg1 + g;
    float a0 = 0.f, a1 = 0.f;
    int ub = hf * 512;
    for (int u = ub; u < ub + 512; u += 2) {
      a0 += ah_s[u]     * wg[(long)u * 128];
      a1 += ah_s[u + 1] * wg[(long)(u + 1) * 128];
    }
    red_s[tid] = a0 + a1;
  }
  __syncthreads();
  if (tid < 128) tanh_s[tid] = tanhf(red_s[tid] + red_s[tid + 128] + P.bg1[tid]);
  __syncthreads();
  if (tid < 64) {
    float tv0 = tanh_s[tid], tv1 = tanh_s[tid + 64];
    float h0 = tv0 * P.Wg2[2 * tid]     + tv1 * P.Wg2[2 * (tid + 64)];
    float h1 = tv0 * P.Wg2[2 * tid + 1] + tv1 * P.Wg2[2 * (tid + 64) + 1];
#pragma unroll
    for (int o = 32; o; o >>= 1) { h0 += __shfl_down(h0, o); h1 += __shfl_down(h1, o); }
    if (tid == 0) {
      float m  = P.mean[b] + expf(h0) * 8.f;
      float sc = expf(h1) * 8.f;
      P.mean[b] = m;
      long pidx = PARAMS_OFF + ((long)b * Tn + t) * 2;
      store_out(P.out, pidx, h0, bf);
      store_out(P.out, pidx + 1, h1, bf);
      bc_s[0] = m; bc_s[1] = sc;
    }
  }
  __syncthreads();
  float m = bc_s[0], sc = bc_s[1];
  int len = P.mlen[b];
  int ci = (int)floorf(fminf(m, 100000.f));
  int l0 = ci - 80; if (l0 < 0) l0 = 0;
  int l1 = ci + 81; if (l1 > len) l1 = len;
  float inv2 = 0.5f / (sc * sc);
  float invZ = 1.f / (2.50662827463100050242f * sc);
  for (int l = l0 + tid; l < l1; l += 256) {
    float d = (float)l - m;
    float al = expf(-d * d * inv2) * invZ;
    alpha_s[l - l0] = al;
    store_out(P.out, ALIGNS_OFF + ((long)b * Tn + t) * Ln + l, al, bf);
  }
  __syncthreads();
  int nl = l1 - l0;
  int e0 = tid * 2;
  float s0 = 0.f, s1 = 0.f;
  if (bf) {
    const unsigned short* mem = (const unsigned short*)P.mem + ((long)b * Ln + l0) * En + e0;
    for (int l = 0; l < nl; ++l) {
      float al = alpha_s[l];
      s0 += al * ldbf(mem, (long)l * En);
      s1 += al * ldbf(mem, (long)l * En + 1);
    }
  } else {
    const float* mem = (const float*)P.mem + ((long)b * Ln + l0) * En + e0;
    for (int l = 0; l < nl; ++l) {
      float al = alpha_s[l];
      s0 += al * mem[(long)l * En];
      s1 += al * mem[(long)l * En + 1];
    }
  }
  unsigned q = (unsigned)f2bf(s0) | ((unsigned)f2bf(s1) << 16);
  __hip_atomic_store((unsigned*)(P.ctx_bf + b * En + e0), q, __ATOMIC_RELAXED, __HIP_MEMORY_SCOPE_AGENT);
  st_store((ST*)P.ctx_all, ((long)t * 64 + b) * En + e0, s0);
  st_store((ST*)P.ctx_all, ((long)t * 64 + b) * En + e0 + 1, s1);
  __syncthreads();
}

// dec LSTM pointwise(t-1): task bb covers 2 batch rows, 8 contiguous u per thread
template<typename ST>
__device__ __forceinline__ void dev_decpw(const Ptrs& P, int t, int bb) {
  int tid = threadIdx.x;
  int b = bb * 2 + (tid >> 7);
  int u0 = (tid & 127) * 8;
  ST* dh_all = (ST*)P.dh_all;
  float gv[4][8];
#pragma unroll
  for (int gt = 0; gt < 4; ++gt) {
    float4 a0 = *(const float4*)(P.bdi + gt * 1024 + u0);
    float4 a1 = *(const float4*)(P.bdi + gt * 1024 + u0 + 4);
    float4 c0 = *(const float4*)(P.bdh + gt * 1024 + u0);
    float4 c1 = *(const float4*)(P.bdh + gt * 1024 + u0 + 4);
    gv[gt][0] = a0.x + c0.x; gv[gt][1] = a0.y + c0.y; gv[gt][2] = a0.z + c0.z; gv[gt][3] = a0.w + c0.w;
    gv[gt][4] = a1.x + c1.x; gv[gt][5] = a1.y + c1.y; gv[gt][6] = a1.z + c1.z; gv[gt][7] = a1.w + c1.w;
  }
#pragma unroll
  for (int kc = 0; kc < DCH; ++kc) {
    const float* pd = P.Pdec + ((long)kc * 64 + b) * G4A + u0;
#pragma unroll
    for (int gt = 0; gt < 4; ++gt) {
      float4 v0 = ldf4_byp(pd + gt * 1024);
      float4 v1 = ldf4_byp(pd + gt * 1024 + 4);
      gv[gt][0] += v0.x; gv[gt][1] += v0.y; gv[gt][2] += v0.z; gv[gt][3] += v0.w;
      gv[gt][4] += v1.x; gv[gt][5] += v1.y; gv[gt][6] += v1.z; gv[gt][7] += v1.w;
    }
  }
  float4 oc0 = *(const float4*)(P.dc + b * 1024 + u0);
  float4 oc1 = *(const float4*)(P.dc + b * 1024 + u0 + 4);
  float oldc[8] = {oc0.x, oc0.y, oc0.z, oc0.w, oc1.x, oc1.y, oc1.z, oc1.w};
  float hh[8], cc[8];
#pragma unroll
  for (int i = 0; i < 8; ++i) {
    float ii = sigm(gv[0][i]), ff = sigm(gv[1][i]), oo = sigm(gv[3][i]);
    cc[i] = ff * oldc[i] + ii * tanhf(gv[2][i]);
    hh[i] = oo * tanhf(cc[i]);
  }
  *(float4*)(P.dc + b * 1024 + u0)     = make_float4(cc[0], cc[1], cc[2], cc[3]);
  *(float4*)(P.dc + b * 1024 + u0 + 4) = make_float4(cc[4], cc[5], cc[6], cc[7]);
  st4_bf_byp(P.dh_bf + b * 1024 + u0,     hh[0], hh[1], hh[2], hh[3]);
  st4_bf_byp(P.dh_bf + b * 1024 + u0 + 4, hh[4], hh[5], hh[6], hh[7]);
#pragma unroll
  for (int i = 0; i < 8; ++i)
    st_store(dh_all, ((long)(t - 1) * 64 + b) * 1024 + u0 + i, hh[i]);
}

// ---------------- the persistent decoder loop (512 blocks, all co-resident) ----------------
template<typename ST>
__global__ __launch_bounds__(256, 2) void k_persist(Ptrs P, int* bar) {
  __shared__ float ah_s[1024];
  __shared__ float red_s[256];
  __shared__ float tanh_s[128];
  __shared__ float bc_s[2];
  __shared__ float alpha_s[176];
  int nb = (int)gridDim.x, bid = (int)blockIdx.x;
  int epoch = 0;
  for (int vb = bid; vb < 512; vb += nb) dev_gemm(P, -1, vb);   // prologue: att gates(0)
  gsync(bar, ++epoch);
  for (int t = 0; t <= Tn; ++t) {
    if (bid < 64)      { if (t < Tn) dev_attpw<ST>(P, t, bid, ah_s, red_s, tanh_s, bc_s, alpha_s); }
    else if (bid < 96) { if (t >= 1) dev_decpw<ST>(P, t, bid - 64); }
    gsync(bar, ++epoch);
    if (t < Tn) { for (int vb = bid; vb < 512; vb += nb) dev_gemm(P, t, vb); }
    gsync(bar, ++epoch);
  }
}

// ---------------- final projection: logits = [dh, ctx] @ W_proj + b ----------------
template<typename ST>
__global__ __launch_bounds__(256) void k_proj(Ptrs P) {
  __shared__ __align__(16) float A_s[64][65];
  __shared__ __align__(16) float W_s[64 * 160];
  int t = blockIdx.x, tid = threadIdx.x;
  int bf = *P.flag;
  const ST* dh_all = (const ST*)P.dh_all;
  const ST* ctx_all = (const ST*)P.ctx_all;
  int tc = tid & 15, tr = tid >> 4;
  int c0 = tc * 10, b0 = tr * 4;
  float acc[4][10];
#pragma unroll
  for (int i = 0; i < 4; ++i)
#pragma unroll
    for (int j = 0; j < 10; ++j) acc[i][j] = 0.f;
  for (int k0 = 0; k0 < KPROJ; k0 += 64) {
    __syncthreads();
    for (int i = tid; i < 64 * 64; i += 256) {
      int b = i >> 6, kk = i & 63;
      int k = k0 + kk;
      float v = (k < Dn) ? st_load(dh_all, ((long)t * 64 + b) * Dn + k)
                         : st_load(ctx_all, ((long)t * 64 + b) * En + (k - Dn));
      A_s[b][kk] = v;
    }
    for (int i = tid; i < 64 * 160; i += 256) {
      int kk = i / 160, c = i - kk * 160;
      W_s[kk * 160 + c] = (c < Vn) ? P.Wpr[(long)(k0 + kk) * Vn + c] : 0.f;
    }
    __syncthreads();
    for (int kk = 0; kk < 64; ++kk) {
      float xs[4];
#pragma unroll
      for (int i = 0; i < 4; ++i) xs[i] = A_s[b0 + i][kk];
#pragma unroll
      for (int j = 0; j < 10; ++j) {
        float w = W_s[kk * 160 + c0 + j];
#pragma unroll
        for (int i = 0; i < 4; ++i) acc[i][j] += xs[i] * w;
      }
    }
  }
#pragma unroll
  for (int i = 0; i < 4; ++i)
#pragma unroll
    for (int j = 0; j < 10; ++j) {
      int c = c0 + j;
      if (c < Vn) {
        int b = b0 + i;
        store_out(P.out, LOGITS_OFF + ((long)b * Tn + t) * Vn + c, acc[i][j] + P.bpr[c], bf);
      }
    }
}

// ---------------- host ----------------
template<typename ST>
static void run_pipeline(const Ptrs& P, int* bar, hipStream_t stream) {
  k_prenet<<<Tn * 2, 256, 0, stream>>>(P, DK1.a, DK1.b, DK2.a, DK2.b);
  k_persist<ST><<<512, 256, 0, stream>>>(P, bar);   // 2 blocks/CU co-resident (LB(256,2))
  k_proj<ST><<<Tn, 256, 0, stream>>>(P);
}

extern "C" void kernel_launch(void* const* d_in, const int* in_sizes, int n_in,
                              void* d_out, int out_size, void* d_ws, size_t ws_size,
                              hipStream_t stream) {
  (void)in_sizes; (void)n_in; (void)out_size;
  char* base = (char*)d_ws;
  int* flag = (int*)base;
  size_t off = 256;
  auto allocf = [&](size_t n) -> float* {
    float* p = (float*)(base + off);
    off += ((n * 4 + 255) / 256) * 256;
    return p;
  };
  auto allocu = [&](size_t n) -> unsigned short* {
    unsigned short* p = (unsigned short*)(base + off);
    off += ((n * 2 + 255) / 256) * 256;
    return p;
  };
  int* bar = (int*)(base + off); off += 2560;   // 576 ints used
  float* Wp1 = allocf(131072);
  float* Wp2 = allocf(65536);
  float* bai = allocf(4096);
  float* bah = allocf(4096);
  float* Wg1 = allocf(131072);
  float* bg1 = allocf(128);
  float* Wg2 = allocf(256);
  float* bdi = allocf(4096);
  float* bdh = allocf(4096);
  float* Wpr = allocf(227328);
  float* bpr = allocf(148);
  unsigned short* PWatt = allocu((size_t)NKB_ATT * 256 * 512);  // bf16 packed weights
  unsigned short* PWdec = allocu((size_t)NKB_DEC * 256 * 512);
  unsigned short* pre_bf = allocu((size_t)Tn * 64 * Pn);
  float* Patt = allocf((size_t)ACH * 64 * G4A);
  float* Pdec = allocf((size_t)DCH * 64 * G4A);
  // zero region: ac, dc, mean (f32) then mirrors (u16), all contiguous
  float* ac = allocf(65536);
  float* dc = allocf(65536);
  float* mean = allocf(64);
  unsigned short* ah_bf = allocu(65536);
  unsigned short* ctx_bf = allocu(32768);
  unsigned short* dh_bf = allocu(65536);
  size_t fixed = off;
  size_t nDH = (size_t)Tn * 64 * Dn, nCX = (size_t)Tn * 64 * En;
  bool f32tier = (fixed + (nDH + nCX) * 4 <= ws_size);
  bool b16tier = (fixed + (nDH + nCX) * 2 <= ws_size);
  if (!f32tier && !b16tier) return;

  Ptrs P;
  P.Wp1=Wp1; P.Wp2=Wp2; P.bai=bai; P.bah=bah; P.Wg1=Wg1; P.bg1=bg1; P.Wg2=Wg2;
  P.bdi=bdi; P.bdh=bdh; P.Wpr=Wpr; P.bpr=bpr;
  P.PWatt=PWatt; P.PWdec=PWdec; P.pre_bf=pre_bf;
  P.ah_bf=ah_bf; P.ctx_bf=ctx_bf; P.dh_bf=dh_bf;
  P.Patt=Patt; P.Pdec=Pdec; P.ac=ac; P.dc=dc; P.mean=mean;
  size_t esz = f32tier ? 4 : 2;
  P.dh_all  = base + fixed;
  P.ctx_all = base + fixed + nDH * esz;
  P.mem = d_in[0]; P.din = d_in[1]; P.mlen = (const int*)d_in[2];
  P.w_ai = d_in[5]; P.w_ah = d_in[6]; P.w_di = d_in[12]; P.w_dh = d_in[13];
  P.flag = flag; P.out = d_out;

  k_detect<<<1, 256, 0, stream>>>(d_in[0], flag);

  struct CV { const void* s; float* d; long n; };
  const CV cv[11] = {
    {d_in[3], Wp1, 131072}, {d_in[4], Wp2, 65536},
    {d_in[7], bai, 4096}, {d_in[8], bah, 4096},
    {d_in[9], Wg1, 131072}, {d_in[10], bg1, 128}, {d_in[11], Wg2, 256},
    {d_in[14], bdi, 4096}, {d_in[15], bdh, 4096},
    {d_in[16], Wpr, 227328}, {d_in[17], bpr, 148},
  };
  for (int i = 0; i < 11; ++i) {
    long g = (cv[i].n + 255) / 256; if (g > 1024) g = 1024;
    k_convert<<<(int)g, 256, 0, stream>>>(cv[i].s, cv[i].d, cv[i].n, flag);
  }
  k_pack<<<(NKB_ATT + NKB_DEC) * 64, 256, 0, stream>>>(P);
  k_zero_f32<<<1, 256, 0, stream>>>((float*)bar, 640);
  // ac(65536)+dc(65536)+mean(64) f32 + mirrors 163840 u16 (=81920 words), contiguous
  k_zero_f32<<<512, 256, 0, stream>>>(ac, 131136 + 81920);
  k_zero_aligns<<<2048, 256, 0, stream>>>(d_out, flag);

  if (f32tier) run_pipeline<float>(P, bar, stream);
  else         run_pipeline<unsigned short>(P, bar, stream);
}

// Round 6
// 59706.067 us; speedup vs baseline: 2.5916x; 1.0736x over previous
//
#include <hip/hip_runtime.h>
#include <math.h>

// ---------------- config ----------------
#define TF_PARTITIONABLE 1   // jax threefry_partitionable (default True since jax 0.4.36)

static constexpr int Bn=64, Ln=512, En=512, Tn=512, Sn=512, Pn=256, An=1024, Dn=1024, Gn=128, Vn=148;
static constexpr int G4A = 4096;            // 4*A == 4*D
static constexpr int KPROJ = Dn + En;       // 1536
static constexpr int KATT = 1792, KDEC = 2560;
static constexpr int ACH = 4, ACK = 448;    // att gates K = 4 chunks x 448
static constexpr int DCH = 4, DCK = 640;    // dec gates K = 4 chunks x 640
static constexpr int NKB_ATT = KATT / 32;   // 56 k-blocks
static constexpr int NKB_DEC = KDEC / 32;   // 80
static constexpr long LOGITS_OFF = 0;
static constexpr long ALIGNS_OFF = (long)Bn*Tn*Vn;               // 4,849,664
static constexpr long PARAMS_OFF = ALIGNS_OFF + (long)Bn*Tn*Ln;  // 21,626,880

using s16x8 = __attribute__((ext_vector_type(8))) short;
using f32x4 = __attribute__((ext_vector_type(4))) float;

// ---------------- threefry2x32 (jax-exact) ----------------
struct TFo { unsigned a, b; };
static constexpr TFo htf(unsigned k1, unsigned k2, unsigned x0, unsigned x1) {
  unsigned ks2 = k1 ^ k2 ^ 0x1BD11BDAu;
  unsigned ks[3] = {k1, k2, ks2};
  const unsigned ra[4] = {13u,15u,26u,6u}, rb[4] = {17u,29u,16u,24u};
  x0 += k1; x1 += k2;
  for (int g = 0; g < 5; ++g) {
    const unsigned* r = (g % 2 == 0) ? ra : rb;
    for (int i = 0; i < 4; ++i) { x0 += x1; x1 = (x1 << r[i]) | (x1 >> (32u - r[i])); x1 ^= x0; }
    x0 += ks[(g+1)%3]; x1 += ks[(g+2)%3] + (unsigned)(g+1);
  }
  return TFo{x0, x1};
}
#if TF_PARTITIONABLE
static constexpr TFo DK1 = htf(0u,42u,0u,0u);
static constexpr TFo DK2 = htf(0u,42u,0u,1u);
#else
static constexpr TFo S02 = htf(0u,42u,0u,2u);
static constexpr TFo S13 = htf(0u,42u,1u,3u);
static constexpr TFo DK1 = TFo{S02.a, S13.a};
static constexpr TFo DK2 = TFo{S02.b, S13.b};
#endif

__device__ __forceinline__ void dtf(unsigned k1, unsigned k2, unsigned x0, unsigned x1,
                                    unsigned& o0, unsigned& o1) {
  unsigned ks2 = k1 ^ k2 ^ 0x1BD11BDAu;
#define TFR(r) { x0 += x1; x1 = (x1<<r)|(x1>>(32-r)); x1 ^= x0; }
  x0 += k1; x1 += k2;
  TFR(13) TFR(15) TFR(26) TFR(6)  x0 += k2;  x1 += ks2 + 1u;
  TFR(17) TFR(29) TFR(16) TFR(24) x0 += ks2; x1 += k1 + 2u;
  TFR(13) TFR(15) TFR(26) TFR(6)  x0 += k1;  x1 += k2 + 3u;
  TFR(17) TFR(29) TFR(16) TFR(24) x0 += k2;  x1 += ks2 + 4u;
  TFR(13) TFR(15) TFR(26) TFR(6)  x0 += ks2; x1 += k1 + 5u;
#undef TFR
  o0 = x0; o1 = x1;
}

__device__ __forceinline__ bool keepmask(unsigned ka, unsigned kb, unsigned j) {
#if TF_PARTITIONABLE
  unsigned o0, o1; dtf(ka, kb, 0u, j, o0, o1);
  return ((o0 ^ o1) >> 31) == 0u;
#else
  const unsigned H = 4202496u;  // (513*64*256)/2
  unsigned o0, o1;
  if (j < H) { dtf(ka, kb, j, j + H, o0, o1); return (o0 >> 31) == 0u; }
  else       { dtf(ka, kb, j - H, j, o0, o1); return (o1 >> 31) == 0u; }
#endif
}

// ---------------- dtype helpers ----------------
__device__ __forceinline__ float ldbf(const unsigned short* p, long i) {
  return __uint_as_float(((unsigned)p[i]) << 16);
}
__device__ __forceinline__ unsigned short f2bf(float v) {
  unsigned x = __float_as_uint(v);
  return (unsigned short)((x + 0x7fffu + ((x >> 16) & 1u)) >> 16);  // RNE
}
__device__ __forceinline__ void store_out(void* out, long i, float v, int bf) {
  if (bf) ((unsigned short*)out)[i] = f2bf(v);
  else    ((float*)out)[i] = v;
}
__device__ __forceinline__ float st_load(const float* p, long i) { return p[i]; }
__device__ __forceinline__ float st_load(const unsigned short* p, long i) { return ldbf(p, i); }
__device__ __forceinline__ void st_store(float* p, long i, float v) { p[i] = v; }
__device__ __forceinline__ void st_store(unsigned short* p, long i, float v) { p[i] = f2bf(v); }
__device__ __forceinline__ float sigm(float x) { return 1.f / (1.f + expf(-x)); }

// ---- L2-bypassing (device-coherent) accessors: relaxed agent-scope atomics ----
__device__ __forceinline__ unsigned long long ldq_byp(const void* p) {
  return __hip_atomic_load((const unsigned long long*)p, __ATOMIC_RELAXED, __HIP_MEMORY_SCOPE_AGENT);
}
__device__ __forceinline__ void stq_byp(void* p, unsigned long long v) {
  __hip_atomic_store((unsigned long long*)p, v, __ATOMIC_RELAXED, __HIP_MEMORY_SCOPE_AGENT);
}
__device__ __forceinline__ s16x8 lda8(const unsigned short* p) {   // 8 bf16 (16B) via 2 u64
  union { unsigned long long q[2]; s16x8 v; } u;
  u.q[0] = ldq_byp(p); u.q[1] = ldq_byp(p + 4);
  return u.v;
}
__device__ __forceinline__ float4 ldf4_byp(const float* p) {       // 4 f32 via 2 u64
  union { unsigned long long q[2]; float4 f; } u;
  u.q[0] = ldq_byp(p); u.q[1] = ldq_byp(p + 2);
  return u.f;
}
__device__ __forceinline__ void st4_bf_byp(unsigned short* p, float a, float b, float c, float d) {
  unsigned long long q = (unsigned long long)f2bf(a) | ((unsigned long long)f2bf(b) << 16)
                       | ((unsigned long long)f2bf(c) << 32) | ((unsigned long long)f2bf(d) << 48);
  stq_byp(p, q);
}
__device__ __forceinline__ void stf_byp(float* p, float v) {
  __hip_atomic_store(p, v, __ATOMIC_RELAXED, __HIP_MEMORY_SCOPE_AGENT);
}

// ---------------- pointer pack ----------------
struct Ptrs {
  const float *Wp1,*Wp2,*bai,*bah,*Wg1,*bg1,*Wg2,*bdi,*bdh,*Wpr,*bpr;
  unsigned short *PWatt,*PWdec,*pre_bf,*ah_bf,*ctx_bf,*dh_bf;
  float *Patt,*Pdec,*ac,*dc,*mean;
  void *dh_all,*ctx_all;
  const void *mem,*din,*w_ai,*w_ah,*w_di,*w_dh;
  const int *mlen; const int *flag; void *out;
};

// ---------------- grid barrier: flag-array + scanner (no RMW contention) ----------------
// flags[256] monotonically-increasing epochs; gen at bar+320. Block 0 wave 0 scans.
__device__ __forceinline__ void gsync(int* flags, int* gen, int epoch) {
  __syncthreads();   // drains vmcnt -> this block's sc1 stores are at the coherent point
  if (blockIdx.x == 0) {
    if (threadIdx.x < 64) {
      if (threadIdx.x == 0)
        __hip_atomic_store(&flags[0], epoch, __ATOMIC_RELAXED, __HIP_MEMORY_SCOPE_AGENT);
      long long t0 = clock64();
      for (;;) {
        bool ok = true;
#pragma unroll
        for (int j = 0; j < 4; ++j) {
          int v = __hip_atomic_load(&flags[threadIdx.x * 4 + j],
                                    __ATOMIC_RELAXED, __HIP_MEMORY_SCOPE_AGENT);
          ok = ok && (v >= epoch);
        }
        if (__all(ok)) break;
        if (clock64() - t0 > (1LL << 31)) break;  // fail visibly, never hang
        __builtin_amdgcn_s_sleep(2);
      }
      if (threadIdx.x == 0)
        __hip_atomic_store(gen, epoch, __ATOMIC_RELAXED, __HIP_MEMORY_SCOPE_AGENT);
    }
  } else {
    if (threadIdx.x == 0) {
      __hip_atomic_store(&flags[blockIdx.x], epoch, __ATOMIC_RELAXED, __HIP_MEMORY_SCOPE_AGENT);
      long long t0 = clock64();
      while (__hip_atomic_load(gen, __ATOMIC_RELAXED, __HIP_MEMORY_SCOPE_AGENT) < epoch) {
        __builtin_amdgcn_s_sleep(8);
        if (clock64() - t0 > (1LL << 31)) break;
      }
    }
  }
  __syncthreads();
}

// ---------------- utility kernels ----------------
__global__ __launch_bounds__(256) void k_detect(const void* mem, int* flag) {
  __shared__ int cnt;
  int tid = threadIdx.x;
  if (tid == 0) cnt = 0;
  __syncthreads();
  const unsigned short* p = (const unsigned short*)mem;
  int local = 0;
  for (int i = tid; i < 1024; i += 256) {
    float f = ldbf(p, 2L * i);
    if (f == f && fabsf(f) > 0.0009f && fabsf(f) < 16.f) local++;
  }
  atomicAdd(&cnt, local);
  __syncthreads();
  if (tid == 0) flag[0] = (cnt > 512) ? 1 : 0;
}

__global__ __launch_bounds__(256) void k_convert(const void* src, float* dst, long n, const int* flag) {
  int bf = *flag;
  long i0 = (long)blockIdx.x * 256 + threadIdx.x, stp = (long)gridDim.x * 256;
  if (bf) { const unsigned short* s = (const unsigned short*)src;
            for (long i = i0; i < n; i += stp) dst[i] = ldbf(s, i); }
  else    { const float* s = (const float*)src;
            for (long i = i0; i < n; i += stp) dst[i] = s[i]; }
}

__global__ __launch_bounds__(256) void k_zero_f32(float* p, long n) {
  for (long i = (long)blockIdx.x * 256 + threadIdx.x; i < n; i += (long)gridDim.x * 256) p[i] = 0.f;
}

__global__ __launch_bounds__(256) void k_zero_aligns(void* out, const int* flag) {
  int bf = *flag;
  unsigned* p; long n;
  if (bf) { p = (unsigned*)out + (ALIGNS_OFF >> 1); n = ((long)Bn*Tn*Ln) >> 1; }
  else    { p = (unsigned*)out + ALIGNS_OFF;        n = (long)Bn*Tn*Ln; }
  for (long i = (long)blockIdx.x * 256 + threadIdx.x; i < n; i += (long)gridDim.x * 256) p[i] = 0u;
}

// ---------------- weight packing: bf16 B-fragment order ----------------
// PW[kblk][nblk][lane][8]: lane l elem j <-> W[kblk*32 + (l>>4)*8 + j][nblk*16 + (l&15)]
__global__ __launch_bounds__(256) void k_pack(Ptrs P) {
  __shared__ float s[32][65];
  int bid = blockIdx.x, tid = threadIdx.x;
  bool att = bid < NKB_ATT * 64;
  int lb = att ? bid : bid - NKB_ATT * 64;
  int kblk = lb >> 6, ng = lb & 63;
  int n0 = ng * 64;
  int bf = *P.flag;
  int split = att ? (Pn + En) : (An + En);
  const void* S0 = att ? P.w_ai : P.w_di;
  const void* S1 = att ? P.w_ah : P.w_dh;
  for (int i = tid; i < 2048; i += 256) {
    int kk = i >> 6, n = i & 63;
    int k = kblk * 32 + kk;
    const void* src = (k < split) ? S0 : S1;
    long idx = (long)(k < split ? k : k - split) * G4A + (n0 + n);
    s[kk][n] = bf ? ldbf((const unsigned short*)src, idx) : ((const float*)src)[idx];
  }
  __syncthreads();
  int lane = tid & 63, tb = tid >> 6;
  unsigned short r[8];
#pragma unroll
  for (int j = 0; j < 8; ++j)
    r[j] = f2bf(s[(lane >> 4) * 8 + j][tb * 16 + (lane & 15)]);
  unsigned short* out = (att ? P.PWatt : P.PWdec) +
      (((long)kblk * 256 + (ng * 4 + tb)) * 64 + lane) * 8;
  *(uint4*)out = *(const uint4*)r;
}

// ---------------- prenet (fused GEMM1+mask1+GEMM2+mask2) -> bf16 ----------------
__global__ __launch_bounds__(256) void k_prenet(Ptrs P, unsigned k1a, unsigned k1b,
                                                unsigned k2a, unsigned k2b) {
  __shared__ __align__(16) float x_s[32 * 17];
  __shared__ __align__(16) float W_s[16 * 256];
  __shared__ __align__(16) float h1_s[32 * 258];
  int bid = blockIdx.x, tid = threadIdx.x;
  int t = bid >> 1, half = bid & 1;
  int bf = *P.flag;
  int tc = tid & 63, tr = tid >> 6;
  int p0 = tc * 4, bl0 = tr * 8;
  float acc[8][4];
#pragma unroll
  for (int i = 0; i < 8; ++i) { acc[i][0]=0; acc[i][1]=0; acc[i][2]=0; acc[i][3]=0; }

  for (int kc = 0; kc < 32; ++kc) {
    __syncthreads();
    for (int i = tid; i < 32 * 16; i += 256) {
      int bl = i >> 4, kk = i & 15;
      int s = kc * 16 + kk;
      float v = 0.f;
      if (t > 0) {
        long idx = ((long)(half * 32 + bl) * Sn + s) * Tn + (t - 1);
        v = bf ? ldbf((const unsigned short*)P.din, idx) : ((const float*)P.din)[idx];
      }
      x_s[bl * 17 + kk] = v;
    }
    for (int i = tid; i < 16 * 256; i += 256) {
      int kk = i >> 8, p = i & 255;
      W_s[kk * 256 + p] = P.Wp1[(long)(kc * 16 + kk) * 256 + p];
    }
    __syncthreads();
    for (int kk = 0; kk < 16; ++kk) {
      float4 w = *(const float4*)(W_s + kk * 256 + p0);
#pragma unroll
      for (int i = 0; i < 8; ++i) {
        float x = x_s[(bl0 + i) * 17 + kk];
        acc[i][0] += x * w.x; acc[i][1] += x * w.y; acc[i][2] += x * w.z; acc[i][3] += x * w.w;
      }
    }
  }
#pragma unroll
  for (int i = 0; i < 8; ++i)
#pragma unroll
    for (int j = 0; j < 4; ++j) {
      int bl = bl0 + i, p = p0 + j, bg = half * 32 + bl;
      float v = fmaxf(acc[i][j], 0.f);
      unsigned ft = (unsigned)(((long)t * 64 + bg) * 256 + p);
      v = keepmask(k1a, k1b, ft) ? 2.f * v : 0.f;
      h1_s[bl * 258 + p] = v;
      acc[i][j] = 0.f;
    }
  __syncthreads();
  for (int kc = 0; kc < 16; ++kc) {
    __syncthreads();
    for (int i = tid; i < 16 * 256; i += 256) {
      int kk = i >> 8, p = i & 255;
      W_s[kk * 256 + p] = P.Wp2[(long)(kc * 16 + kk) * 256 + p];
    }
    __syncthreads();
    for (int kk = 0; kk < 16; ++kk) {
      float4 w = *(const float4*)(W_s + kk * 256 + p0);
      int s = kc * 16 + kk;
#pragma unroll
      for (int i = 0; i < 8; ++i) {
        float x = h1_s[(bl0 + i) * 258 + s];
        acc[i][0] += x * w.x; acc[i][1] += x * w.y; acc[i][2] += x * w.z; acc[i][3] += x * w.w;
      }
    }
  }
#pragma unroll
  for (int i = 0; i < 8; ++i)
#pragma unroll
    for (int j = 0; j < 4; ++j) {
      int bg = half * 32 + bl0 + i, p = p0 + j;
      float v = fmaxf(acc[i][j], 0.f);
      unsigned ft = (unsigned)(((long)t * 64 + bg) * 256 + p);
      v = keepmask(k2a, k2b, ft) ? 2.f * v : 0.f;
      P.pre_bf[((long)t * 64 + bg) * 256 + p] = f2bf(v);
    }
}

// ---------------- device phase bodies (1024-thread blocks, 16 waves) ----------------
// gate GEMM: A staged to LDS once (sc1), B weights cached (L2-resident), 2-deep B prefetch.
// Block = (col-group of 128 cols, kc chunk). Wave pair shares a B tile, covers half the rows.
template<bool ATT>
__device__ __forceinline__ void dev_gemm2(const Ptrs& P, int t, int lb, unsigned short* a_lds) {
  constexpr int CK    = ATT ? ACK : DCK;      // 448 / 640
  constexpr int SUBK  = ATT ? 224 : 320;      // K per LDS substage
  constexpr int NKS   = SUBK / 32;            // 7 / 10
  constexpr int PITCH = SUBK + 8;             // +16B pad -> 2-way banks (free)
  constexpr int NG    = 64 * (SUBK / 8);      // 16B stage groups
  int tid = threadIdx.x;
  int cg = lb >> 2, kc = lb & 3;
  int lane = tid & 63, w = tid >> 6;          // 16 waves
  int nblk = cg * 8 + (w >> 1);               // 16-col block
  int mh = w & 1;                             // row half: rows mh*32..mh*32+31
  const unsigned short* PW = ATT ? P.PWatt : P.PWdec;
  const unsigned short* pre_t = P.pre_bf + (long)(t + 1) * 64 * Pn;
  int rlo = lane & 15, khi8 = (lane >> 4) * 8;

  auto aaddr = [&](int kglob, int row) -> const unsigned short* {
    const unsigned short* seg; int stride; int off;
    if (ATT) {
      if (kglob < Pn)           { seg = pre_t;    stride = Pn; off = kglob; }
      else if (kglob < Pn + En) { seg = P.ctx_bf; stride = En; off = kglob - Pn; }
      else                      { seg = P.ah_bf;  stride = An; off = kglob - Pn - En; }
    } else {
      if (kglob < An)           { seg = P.ah_bf;  stride = An; off = kglob; }
      else if (kglob < An + En) { seg = P.ctx_bf; stride = En; off = kglob - An; }
      else                      { seg = P.dh_bf;  stride = Dn; off = kglob - An - En; }
    }
    return seg + (long)row * stride + off;
  };

  f32x4 acc[2];
  acc[0] = f32x4{0.f, 0.f, 0.f, 0.f};
  acc[1] = f32x4{0.f, 0.f, 0.f, 0.f};

#pragma unroll
  for (int sub = 0; sub < 2; ++sub) {
    int k0 = kc * CK + sub * SUBK;
    __syncthreads();                           // previous LDS contents consumed
    for (int i = tid; i < NG; i += 1024) {     // stage A chunk (sc1 burst -> LDS)
      int row = i / (SUBK / 8), kg = i - row * (SUBK / 8);
      s16x8 v = lda8(aaddr(k0 + kg * 8, row));
      *(s16x8*)(a_lds + row * PITCH + kg * 8) = v;
    }
    __syncthreads();
    const unsigned short* bptr = PW + (((long)(k0 >> 5) * 256 + nblk) * 64 + lane) * 8;
    s16x8 bb0 = *(const s16x8*)bptr;
    s16x8 bb1 = *(const s16x8*)(bptr + 131072);   // kblk stride = 256*64*8 elems
#pragma unroll
    for (int kb = 0; kb < NKS; ++kb) {
      s16x8 bcur = (kb & 1) ? bb1 : bb0;
      if (kb + 2 < NKS) {
        s16x8 nb = *(const s16x8*)(bptr + (long)(kb + 2) * 131072);
        if (kb & 1) bb1 = nb; else bb0 = nb;
      }
      int abase = kb * 32 + khi8;
#pragma unroll
      for (int mb = 0; mb < 2; ++mb) {
        s16x8 a = *(const s16x8*)(a_lds + ((mh * 2 + mb) * 16 + rlo) * PITCH + abase);
        acc[mb] = __builtin_amdgcn_mfma_f32_16x16x32_bf16(a, bcur, acc[mb], 0, 0, 0);
      }
    }
  }
  float* Pout = (ATT ? P.Patt : P.Pdec) + (long)kc * 64 * G4A;
  int col = nblk * 16 + rlo, rbase = (lane >> 4) * 4;
#pragma unroll
  for (int mb = 0; mb < 2; ++mb)
#pragma unroll
    for (int r = 0; r < 4; ++r)
      stf_byp(&Pout[(long)((mh * 2 + mb) * 16 + rbase + r) * G4A + col], acc[mb][r]);
}

// att LSTM pointwise(t) + GMM + alpha + ctx; 4 batch rows per 1024-thread block.
template<typename ST>
__device__ __forceinline__ void dev_attpw2(const Ptrs& P, int t, int bbase,
    float* ah_sh, float* red_sh, float* tanh_sh, float* bc_sh, float* al_sh) {
  int tid = threadIdx.x;
  int h = tid >> 8, ltid = tid & 255;
  int b = bbase + h;
  float* ah_s = ah_sh + h * 1024;
  float* red_s = red_sh + h * 256;
  float* tanh_s = tanh_sh + h * 128;
  float* bc_s = bc_sh + h * 2;
  float* alpha_s = al_sh + h * 176;
  int bf = *P.flag;
  int u0 = ltid * 4;
  float gv[4][4];
#pragma unroll
  for (int gt = 0; gt < 4; ++gt) {
    float4 a = *(const float4*)(P.bai + gt * 1024 + u0);
    float4 c = *(const float4*)(P.bah + gt * 1024 + u0);
    gv[gt][0] = a.x + c.x; gv[gt][1] = a.y + c.y; gv[gt][2] = a.z + c.z; gv[gt][3] = a.w + c.w;
  }
#pragma unroll
  for (int kc = 0; kc < ACH; ++kc) {
    const float* pa = P.Patt + ((long)kc * 64 + b) * G4A + u0;
#pragma unroll
    for (int gt = 0; gt < 4; ++gt) {
      float4 v = ldf4_byp(pa + gt * 1024);
      gv[gt][0] += v.x; gv[gt][1] += v.y; gv[gt][2] += v.z; gv[gt][3] += v.w;
    }
  }
  float4 oc = *(const float4*)(P.ac + b * 1024 + u0);
  float oldc[4] = {oc.x, oc.y, oc.z, oc.w};
  float hh[4], cc[4];
#pragma unroll
  for (int i = 0; i < 4; ++i) {
    float ii = sigm(gv[0][i]), ff = sigm(gv[1][i]), oo = sigm(gv[3][i]);
    cc[i] = ff * oldc[i] + ii * tanhf(gv[2][i]);
    hh[i] = oo * tanhf(cc[i]);
    ah_s[u0 + i] = hh[i];
  }
  *(float4*)(P.ac + b * 1024 + u0) = make_float4(cc[0], cc[1], cc[2], cc[3]);
  st4_bf_byp(P.ah_bf + b * 1024 + u0, hh[0], hh[1], hh[2], hh[3]);
  __syncthreads();
  // GMM hidden: tanh(ah @ W_g1 + b_g1)
  {
    int g = ltid & 127, hf = ltid >> 7;
    const float* wg = P.Wg1 + g;
    float a0 = 0.f, a1 = 0.f;
    int ub = hf * 512;
    for (int u = ub; u < ub + 512; u += 2) {
      a0 += ah_s[u]     * wg[(long)u * 128];
      a1 += ah_s[u + 1] * wg[(long)(u + 1) * 128];
    }
    red_s[ltid] = a0 + a1;
  }
  __syncthreads();
  if (ltid < 128) tanh_s[ltid] = tanhf(red_s[ltid] + red_s[ltid + 128] + P.bg1[ltid]);
  __syncthreads();
  if (ltid < 64) {
    float tv0 = tanh_s[ltid], tv1 = tanh_s[ltid + 64];
    float h0 = tv0 * P.Wg2[2 * ltid]     + tv1 * P.Wg2[2 * (ltid + 64)];
    float h1 = tv0 * P.Wg2[2 * ltid + 1] + tv1 * P.Wg2[2 * (ltid + 64) + 1];
#pragma unroll
    for (int o = 32; o; o >>= 1) { h0 += __shfl_down(h0, o); h1 += __shfl_down(h1, o); }
    if (ltid == 0) {
      float m  = P.mean[b] + expf(h0) * 8.f;
      float sc = expf(h1) * 8.f;
      P.mean[b] = m;
      long pidx = PARAMS_OFF + ((long)b * Tn + t) * 2;
      store_out(P.out, pidx, h0, bf);
      store_out(P.out, pidx + 1, h1, bf);
      bc_s[0] = m; bc_s[1] = sc;
    }
  }
  __syncthreads();
  float m = bc_s[0], sc = bc_s[1];
  int len = P.mlen[b];
  int ci = (int)floorf(fminf(m, 100000.f));
  int l0 = ci - 80; if (l0 < 0) l0 = 0;
  int l1 = ci + 81; if (l1 > len) l1 = len;
  float inv2 = 0.5f / (sc * sc);
  float invZ = 1.f / (2.50662827463100050242f * sc);
  for (int l = l0 + ltid; l < l1; l += 256) {
    float d = (float)l - m;
    float al = expf(-d * d * inv2) * invZ;
    alpha_s[l - l0] = al;
    store_out(P.out, ALIGNS_OFF + ((long)b * Tn + t) * Ln + l, al, bf);
  }
  __syncthreads();
  int nl = l1 - l0;
  int e0 = ltid * 2;
  float s0 = 0.f, s1 = 0.f;
  if (bf) {
    const unsigned short* mem = (const unsigned short*)P.mem + ((long)b * Ln + l0) * En + e0;
    for (int l = 0; l < nl; ++l) {
      float al = alpha_s[l];
      s0 += al * ldbf(mem, (long)l * En);
      s1 += al * ldbf(mem, (long)l * En + 1);
    }
  } else {
    const float* mem = (const float*)P.mem + ((long)b * Ln + l0) * En + e0;
    for (int l = 0; l < nl; ++l) {
      float al = alpha_s[l];
      s0 += al * mem[(long)l * En];
      s1 += al * mem[(long)l * En + 1];
    }
  }
  unsigned q = (unsigned)f2bf(s0) | ((unsigned)f2bf(s1) << 16);
  __hip_atomic_store((unsigned*)(P.ctx_bf + b * En + e0), q, __ATOMIC_RELAXED, __HIP_MEMORY_SCOPE_AGENT);
  st_store((ST*)P.ctx_all, ((long)t * 64 + b) * En + e0, s0);
  st_store((ST*)P.ctx_all, ((long)t * 64 + b) * En + e0 + 1, s1);
  __syncthreads();
}

// dec LSTM pointwise(t-1): 8 batch rows per 1024-thread block
template<typename ST>
__device__ __forceinline__ void dev_decpw2(const Ptrs& P, int t, int bb) {
  int tid = threadIdx.x;
  int b = bb * 8 + (tid >> 7);
  int u0 = (tid & 127) * 8;
  ST* dh_all = (ST*)P.dh_all;
  float gv[4][8];
#pragma unroll
  for (int gt = 0; gt < 4; ++gt) {
    float4 a0 = *(const float4*)(P.bdi + gt * 1024 + u0);
    float4 a1 = *(const float4*)(P.bdi + gt * 1024 + u0 + 4);
    float4 c0 = *(const float4*)(P.bdh + gt * 1024 + u0);
    float4 c1 = *(const float4*)(P.bdh + gt * 1024 + u0 + 4);
    gv[gt][0] = a0.x + c0.x; gv[gt][1] = a0.y + c0.y; gv[gt][2] = a0.z + c0.z; gv[gt][3] = a0.w + c0.w;
    gv[gt][4] = a1.x + c1.x; gv[gt][5] = a1.y + c1.y; gv[gt][6] = a1.z + c1.z; gv[gt][7] = a1.w + c1.w;
  }
#pragma unroll
  for (int kc = 0; kc < DCH; ++kc) {
    const float* pd = P.Pdec + ((long)kc * 64 + b) * G4A + u0;
#pragma unroll
    for (int gt = 0; gt < 4; ++gt) {
      float4 v0 = ldf4_byp(pd + gt * 1024);
      float4 v1 = ldf4_byp(pd + gt * 1024 + 4);
      gv[gt][0] += v0.x; gv[gt][1] += v0.y; gv[gt][2] += v0.z; gv[gt][3] += v0.w;
      gv[gt][4] += v1.x; gv[gt][5] += v1.y; gv[gt][6] += v1.z; gv[gt][7] += v1.w;
    }
  }
  float4 oc0 = *(const float4*)(P.dc + b * 1024 + u0);
  float4 oc1 = *(const float4*)(P.dc + b * 1024 + u0 + 4);
  float oldc[8] = {oc0.x, oc0.y, oc0.z, oc0.w, oc1.x, oc1.y, oc1.z, oc1.w};
  float hh[8], cc[8];
#pragma unroll
  for (int i = 0; i < 8; ++i) {
    float ii = sigm(gv[0][i]), ff = sigm(gv[1][i]), oo = sigm(gv[3][i]);
    cc[i] = ff * oldc[i] + ii * tanhf(gv[2][i]);
    hh[i] = oo * tanhf(cc[i]);
  }
  *(float4*)(P.dc + b * 1024 + u0)     = make_float4(cc[0], cc[1], cc[2], cc[3]);
  *(float4*)(P.dc + b * 1024 + u0 + 4) = make_float4(cc[4], cc[5], cc[6], cc[7]);
  st4_bf_byp(P.dh_bf + b * 1024 + u0,     hh[0], hh[1], hh[2], hh[3]);
  st4_bf_byp(P.dh_bf + b * 1024 + u0 + 4, hh[4], hh[5], hh[6], hh[7]);
#pragma unroll
  for (int i = 0; i < 8; ++i)
    st_store(dh_all, ((long)(t - 1) * 64 + b) * 1024 + u0 + i, hh[i]);
}

// ---------------- the persistent decoder loop: 256 blocks x 1024 threads ----------------
template<typename ST>
__global__ __launch_bounds__(1024, 4) void k_persist(Ptrs P, int* bar) {
  __shared__ __align__(16) unsigned short a_lds[64 * 328];  // 41,984 B (dec pitch)
  __shared__ float ah_sh[4 * 1024];
  __shared__ float red_sh[4 * 256];
  __shared__ float tanh_sh[4 * 128];
  __shared__ float bc_sh[4 * 2];
  __shared__ float al_sh[4 * 176];
  int bid = (int)blockIdx.x;
  int* flags = bar;
  int* gen = bar + 320;
  int epoch = 0;
  if (bid < 128) dev_gemm2<true>(P, -1, bid, a_lds);       // prologue: att gates(0)
  gsync(flags, gen, ++epoch);
  for (int t = 0; t <= Tn; ++t) {
    // P1: att pointwise(t)+GMM+alpha+ctx | dec pointwise(t-1)
    if (bid < 16)      { if (t < Tn) dev_attpw2<ST>(P, t, bid * 4, ah_sh, red_sh, tanh_sh, bc_sh, al_sh); }
    else if (bid < 24) { if (t >= 1) dev_decpw2<ST>(P, t, bid - 16); }
    gsync(flags, gen, ++epoch);
    // P2: att gates(t+1) + dec gates(t)
    if (t < Tn) {
      if (bid < 128) { if (t + 1 < Tn) dev_gemm2<true>(P, t, bid, a_lds); }
      else           { dev_gemm2<false>(P, t, bid - 128, a_lds); }
    }
    gsync(flags, gen, ++epoch);
  }
}

// ---------------- final projection: logits = [dh, ctx] @ W_proj + b ----------------
template<typename ST>
__global__ __launch_bounds__(256) void k_proj(Ptrs P) {
  __shared__ __align__(16) float A_s[64][65];
  __shared__ __align__(16) float W_s[64 * 160];
  int t = blockIdx.x, tid = threadIdx.x;
  int bf = *P.flag;
  const ST* dh_all = (const ST*)P.dh_all;
  const ST* ctx_all = (const ST*)P.ctx_all;
  int tc = tid & 15, tr = tid >> 4;
  int c0 = tc * 10, b0 = tr * 4;
  float acc[4][10];
#pragma unroll
  for (int i = 0; i < 4; ++i)
#pragma unroll
    for (int j = 0; j < 10; ++j) acc[i][j] = 0.f;
  for (int k0 = 0; k0 < KPROJ; k0 += 64) {
    __syncthreads();
    for (int i = tid; i < 64 * 64; i += 256) {
      int b = i >> 6, kk = i & 63;
      int k = k0 + kk;
      float v = (k < Dn) ? st_load(dh_all, ((long)t * 64 + b) * Dn + k)
                         : st_load(ctx_all, ((long)t * 64 + b) * En + (k - Dn));
      A_s[b][kk] = v;
    }
    for (int i = tid; i < 64 * 160; i += 256) {
      int kk = i / 160, c = i - kk * 160;
      W_s[kk * 160 + c] = (c < Vn) ? P.Wpr[(long)(k0 + kk) * Vn + c] : 0.f;
    }
    __syncthreads();
    for (int kk = 0; kk < 64; ++kk) {
      float xs[4];
#pragma unroll
      for (int i = 0; i < 4; ++i) xs[i] = A_s[b0 + i][kk];
#pragma unroll
      for (int j = 0; j < 10; ++j) {
        float w = W_s[kk * 160 + c0 + j];
#pragma unroll
        for (int i = 0; i < 4; ++i) acc[i][j] += xs[i] * w;
      }
    }
  }
#pragma unroll
  for (int i = 0; i < 4; ++i)
#pragma unroll
    for (int j = 0; j < 10; ++j) {
      int c = c0 + j;
      if (c < Vn) {
        int b = b0 + i;
        store_out(P.out, LOGITS_OFF + ((long)b * Tn + t) * Vn + c, acc[i][j] + P.bpr[c], bf);
      }
    }
}

// ---------------- host ----------------
template<typename ST>
static void run_pipeline(const Ptrs& P, int* bar, hipStream_t stream) {
  k_prenet<<<Tn * 2, 256, 0, stream>>>(P, DK1.a, DK1.b, DK2.a, DK2.b);
  k_persist<ST><<<256, 1024, 0, stream>>>(P, bar);
  k_proj<ST><<<Tn, 256, 0, stream>>>(P);
}

extern "C" void kernel_launch(void* const* d_in, const int* in_sizes, int n_in,
                              void* d_out, int out_size, void* d_ws, size_t ws_size,
                              hipStream_t stream) {
  (void)in_sizes; (void)n_in; (void)out_size;
  char* base = (char*)d_ws;
  int* flag = (int*)base;
  size_t off = 256;
  auto allocf = [&](size_t n) -> float* {
    float* p = (float*)(base + off);
    off += ((n * 4 + 255) / 256) * 256;
    return p;
  };
  auto allocu = [&](size_t n) -> unsigned short* {
    unsigned short* p = (unsigned short*)(base + off);
    off += ((n * 2 + 255) / 256) * 256;
    return p;
  };
  int* bar = (int*)(base + off); off += 2560;   // flags[256] + gen at +320
  float* Wp1 = allocf(131072);
  float* Wp2 = allocf(65536);
  float* bai = allocf(4096);
  float* bah = allocf(4096);
  float* Wg1 = allocf(131072);
  float* bg1 = allocf(128);
  float* Wg2 = allocf(256);
  float* bdi = allocf(4096);
  float* bdh = allocf(4096);
  float* Wpr = allocf(227328);
  float* bpr = allocf(148);
  unsigned short* PWatt = allocu((size_t)NKB_ATT * 256 * 512);  // bf16 packed weights
  unsigned short* PWdec = allocu((size_t)NKB_DEC * 256 * 512);
  unsigned short* pre_bf = allocu((size_t)Tn * 64 * Pn);
  float* Patt = allocf((size_t)ACH * 64 * G4A);
  float* Pdec = allocf((size_t)DCH * 64 * G4A);
  // zero region: ac, dc, mean (f32) then bf16 mirrors, all contiguous
  float* ac = allocf(65536);
  float* dc = allocf(65536);
  float* mean = allocf(64);
  unsigned short* ah_bf = allocu(65536);
  unsigned short* ctx_bf = allocu(32768);
  unsigned short* dh_bf = allocu(65536);
  size_t fixed = off;
  size_t nDH = (size_t)Tn * 64 * Dn, nCX = (size_t)Tn * 64 * En;
  bool f32tier = (fixed + (nDH + nCX) * 4 <= ws_size);
  bool b16tier = (fixed + (nDH + nCX) * 2 <= ws_size);
  if (!f32tier && !b16tier) return;

  Ptrs P;
  P.Wp1=Wp1; P.Wp2=Wp2; P.bai=bai; P.bah=bah; P.Wg1=Wg1; P.bg1=bg1; P.Wg2=Wg2;
  P.bdi=bdi; P.bdh=bdh; P.Wpr=Wpr; P.bpr=bpr;
  P.PWatt=PWatt; P.PWdec=PWdec; P.pre_bf=pre_bf;
  P.ah_bf=ah_bf; P.ctx_bf=ctx_bf; P.dh_bf=dh_bf;
  P.Patt=Patt; P.Pdec=Pdec; P.ac=ac; P.dc=dc; P.mean=mean;
  size_t esz = f32tier ? 4 : 2;
  P.dh_all  = base + fixed;
  P.ctx_all = base + fixed + nDH * esz;
  P.mem = d_in[0]; P.din = d_in[1]; P.mlen = (const int*)d_in[2];
  P.w_ai = d_in[5]; P.w_ah = d_in[6]; P.w_di = d_in[12]; P.w_dh = d_in[13];
  P.flag = flag; P.out = d_out;

  k_detect<<<1, 256, 0, stream>>>(d_in[0], flag);

  struct CV { const void* s; float* d; long n; };
  const CV cv[11] = {
    {d_in[3], Wp1, 131072}, {d_in[4], Wp2, 65536},
    {d_in[7], bai, 4096}, {d_in[8], bah, 4096},
    {d_in[9], Wg1, 131072}, {d_in[10], bg1, 128}, {d_in[11], Wg2, 256},
    {d_in[14], bdi, 4096}, {d_in[15], bdh, 4096},
    {d_in[16], Wpr, 227328}, {d_in[17], bpr, 148},
  };
  for (int i = 0; i < 11; ++i) {
    long g = (cv[i].n + 255) / 256; if (g > 1024) g = 1024;
    k_convert<<<(int)g, 256, 0, stream>>>(cv[i].s, cv[i].d, cv[i].n, flag);
  }
  k_pack<<<(NKB_ATT + NKB_DEC) * 64, 256, 0, stream>>>(P);
  k_zero_f32<<<1, 256, 0, stream>>>((float*)bar, 640);
  // ac(65536)+dc(65536)+mean(64) f32 + mirrors 163840 u16 (=81920 words), contiguous
  k_zero_f32<<<512, 256, 0, stream>>>(ac, 131136 + 81920);
  k_zero_aligns<<<2048, 256, 0, stream>>>(d_out, flag);

  if (f32tier) run_pipeline<float>(P, bar, stream);
  else         run_pipeline<unsigned short>(P, bar, stream);
}

// Round 7
// 17322.649 us; speedup vs baseline: 8.9325x; 3.4467x over previous
//
#include <hip/hip_runtime.h>
#include <math.h>

// ---------------- config ----------------
#define TF_PARTITIONABLE 1   // jax threefry_partitionable (default True since jax 0.4.36)

static constexpr int Bn=64, Ln=512, En=512, Tn=512, Sn=512, Pn=256, An=1024, Dn=1024, Gn=128, Vn=148;
static constexpr int G4A = 4096;            // 4*A == 4*D
static constexpr int KPROJ = Dn + En;       // 1536
static constexpr int KATT = 1792, KDEC = 2560;
static constexpr int ACH = 4, ACK = 448;    // att gates K = 4 chunks x 448
static constexpr int DCH = 4, DCK = 640;    // dec gates K = 4 chunks x 640
static constexpr int NKB_ATT = KATT / 32;   // 56 k-blocks
static constexpr int NKB_DEC = KDEC / 32;   // 80
static constexpr long LOGITS_OFF = 0;
static constexpr long ALIGNS_OFF = (long)Bn*Tn*Vn;               // 4,849,664
static constexpr long PARAMS_OFF = ALIGNS_OFF + (long)Bn*Tn*Ln;  // 21,626,880

using s16x8 = __attribute__((ext_vector_type(8))) short;
using f32x4 = __attribute__((ext_vector_type(4))) float;

// ---------------- threefry2x32 (jax-exact) ----------------
struct TFo { unsigned a, b; };
static constexpr TFo htf(unsigned k1, unsigned k2, unsigned x0, unsigned x1) {
  unsigned ks2 = k1 ^ k2 ^ 0x1BD11BDAu;
  unsigned ks[3] = {k1, k2, ks2};
  const unsigned ra[4] = {13u,15u,26u,6u}, rb[4] = {17u,29u,16u,24u};
  x0 += k1; x1 += k2;
  for (int g = 0; g < 5; ++g) {
    const unsigned* r = (g % 2 == 0) ? ra : rb;
    for (int i = 0; i < 4; ++i) { x0 += x1; x1 = (x1 << r[i]) | (x1 >> (32u - r[i])); x1 ^= x0; }
    x0 += ks[(g+1)%3]; x1 += ks[(g+2)%3] + (unsigned)(g+1);
  }
  return TFo{x0, x1};
}
#if TF_PARTITIONABLE
static constexpr TFo DK1 = htf(0u,42u,0u,0u);
static constexpr TFo DK2 = htf(0u,42u,0u,1u);
#else
static constexpr TFo S02 = htf(0u,42u,0u,2u);
static constexpr TFo S13 = htf(0u,42u,1u,3u);
static constexpr TFo DK1 = TFo{S02.a, S13.a};
static constexpr TFo DK2 = TFo{S02.b, S13.b};
#endif

__device__ __forceinline__ void dtf(unsigned k1, unsigned k2, unsigned x0, unsigned x1,
                                    unsigned& o0, unsigned& o1) {
  unsigned ks2 = k1 ^ k2 ^ 0x1BD11BDAu;
#define TFR(r) { x0 += x1; x1 = (x1<<r)|(x1>>(32-r)); x1 ^= x0; }
  x0 += k1; x1 += k2;
  TFR(13) TFR(15) TFR(26) TFR(6)  x0 += k2;  x1 += ks2 + 1u;
  TFR(17) TFR(29) TFR(16) TFR(24) x0 += ks2; x1 += k1 + 2u;
  TFR(13) TFR(15) TFR(26) TFR(6)  x0 += k1;  x1 += k2 + 3u;
  TFR(17) TFR(29) TFR(16) TFR(24) x0 += k2;  x1 += ks2 + 4u;
  TFR(13) TFR(15) TFR(26) TFR(6)  x0 += ks2; x1 += k1 + 5u;
#undef TFR
  o0 = x0; o1 = x1;
}

__device__ __forceinline__ bool keepmask(unsigned ka, unsigned kb, unsigned j) {
#if TF_PARTITIONABLE
  unsigned o0, o1; dtf(ka, kb, 0u, j, o0, o1);
  return ((o0 ^ o1) >> 31) == 0u;
#else
  const unsigned H = 4202496u;  // (513*64*256)/2
  unsigned o0, o1;
  if (j < H) { dtf(ka, kb, j, j + H, o0, o1); return (o0 >> 31) == 0u; }
  else       { dtf(ka, kb, j - H, j, o0, o1); return (o1 >> 31) == 0u; }
#endif
}

// ---------------- dtype helpers ----------------
__device__ __forceinline__ float ldbf(const unsigned short* p, long i) {
  return __uint_as_float(((unsigned)p[i]) << 16);
}
__device__ __forceinline__ unsigned short f2bf(float v) {
  unsigned x = __float_as_uint(v);
  return (unsigned short)((x + 0x7fffu + ((x >> 16) & 1u)) >> 16);  // RNE
}
__device__ __forceinline__ void store_out(void* out, long i, float v, int bf) {
  if (bf) ((unsigned short*)out)[i] = f2bf(v);
  else    ((float*)out)[i] = v;
}
__device__ __forceinline__ float st_load(const float* p, long i) { return p[i]; }
__device__ __forceinline__ float st_load(const unsigned short* p, long i) { return ldbf(p, i); }
__device__ __forceinline__ void st_store(float* p, long i, float v) { p[i] = v; }
__device__ __forceinline__ void st_store(unsigned short* p, long i, float v) { p[i] = f2bf(v); }
__device__ __forceinline__ float sigm(float x) { return 1.f / (1.f + expf(-x)); }
__device__ __forceinline__ void st4bf(unsigned short* p, float a, float b, float c, float d) {
  union { unsigned short u[4]; uint2 v; } q;
  q.u[0] = f2bf(a); q.u[1] = f2bf(b); q.u[2] = f2bf(c); q.u[3] = f2bf(d);
  *(uint2*)p = q.v;
}

// ---------------- pointer pack ----------------
struct Ptrs {
  const float *Wp1,*Wp2,*bai,*bah,*Wg1,*bg1,*Wg2,*bdi,*bdh,*Wpr,*bpr;
  unsigned short *PWatt,*PWdec,*pre_bf,*ah_bf,*ctx_bf,*dh_bf;
  float *Patt,*Pdec,*ac,*dc,*mean;
  void *dh_all,*ctx_all;
  const void *mem,*din,*w_ai,*w_ah,*w_di,*w_dh;
  const int *mlen; const int *flag; void *out;
};

// ---------------- utility kernels ----------------
__global__ __launch_bounds__(256) void k_detect(const void* mem, int* flag) {
  __shared__ int cnt;
  int tid = threadIdx.x;
  if (tid == 0) cnt = 0;
  __syncthreads();
  const unsigned short* p = (const unsigned short*)mem;
  int local = 0;
  for (int i = tid; i < 1024; i += 256) {
    float f = ldbf(p, 2L * i);
    if (f == f && fabsf(f) > 0.0009f && fabsf(f) < 16.f) local++;
  }
  atomicAdd(&cnt, local);
  __syncthreads();
  if (tid == 0) flag[0] = (cnt > 512) ? 1 : 0;
}

__global__ __launch_bounds__(256) void k_convert(const void* src, float* dst, long n, const int* flag) {
  int bf = *flag;
  long i0 = (long)blockIdx.x * 256 + threadIdx.x, stp = (long)gridDim.x * 256;
  if (bf) { const unsigned short* s = (const unsigned short*)src;
            for (long i = i0; i < n; i += stp) dst[i] = ldbf(s, i); }
  else    { const float* s = (const float*)src;
            for (long i = i0; i < n; i += stp) dst[i] = s[i]; }
}

__global__ __launch_bounds__(256) void k_zero_f32(float* p, long n) {
  for (long i = (long)blockIdx.x * 256 + threadIdx.x; i < n; i += (long)gridDim.x * 256) p[i] = 0.f;
}

__global__ __launch_bounds__(256) void k_zero_aligns(void* out, const int* flag) {
  int bf = *flag;
  unsigned* p; long n;
  if (bf) { p = (unsigned*)out + (ALIGNS_OFF >> 1); n = ((long)Bn*Tn*Ln) >> 1; }
  else    { p = (unsigned*)out + ALIGNS_OFF;        n = (long)Bn*Tn*Ln; }
  for (long i = (long)blockIdx.x * 256 + threadIdx.x; i < n; i += (long)gridDim.x * 256) p[i] = 0u;
}

// ---------------- weight packing: bf16 B-fragment order ----------------
// PW[kblk][nblk][lane][8]: lane l elem j <-> W[kblk*32 + (l>>4)*8 + j][nblk*16 + (l&15)]
__global__ __launch_bounds__(256) void k_pack(Ptrs P) {
  __shared__ float s[32][65];
  int bid = blockIdx.x, tid = threadIdx.x;
  bool att = bid < NKB_ATT * 64;
  int lb = att ? bid : bid - NKB_ATT * 64;
  int kblk = lb >> 6, ng = lb & 63;
  int n0 = ng * 64;
  int bf = *P.flag;
  int split = att ? (Pn + En) : (An + En);
  const void* S0 = att ? P.w_ai : P.w_di;
  const void* S1 = att ? P.w_ah : P.w_dh;
  for (int i = tid; i < 2048; i += 256) {
    int kk = i >> 6, n = i & 63;
    int k = kblk * 32 + kk;
    const void* src = (k < split) ? S0 : S1;
    long idx = (long)(k < split ? k : k - split) * G4A + (n0 + n);
    s[kk][n] = bf ? ldbf((const unsigned short*)src, idx) : ((const float*)src)[idx];
  }
  __syncthreads();
  int lane = tid & 63, tb = tid >> 6;
  unsigned short r[8];
#pragma unroll
  for (int j = 0; j < 8; ++j)
    r[j] = f2bf(s[(lane >> 4) * 8 + j][tb * 16 + (lane & 15)]);
  unsigned short* out = (att ? P.PWatt : P.PWdec) +
      (((long)kblk * 256 + (ng * 4 + tb)) * 64 + lane) * 8;
  *(uint4*)out = *(const uint4*)r;
}

// ---------------- prenet (fused GEMM1+mask1+GEMM2+mask2) -> bf16 ----------------
__global__ __launch_bounds__(256) void k_prenet(Ptrs P, unsigned k1a, unsigned k1b,
                                                unsigned k2a, unsigned k2b) {
  __shared__ __align__(16) float x_s[32 * 17];
  __shared__ __align__(16) float W_s[16 * 256];
  __shared__ __align__(16) float h1_s[32 * 258];
  int bid = blockIdx.x, tid = threadIdx.x;
  int t = bid >> 1, half = bid & 1;
  int bf = *P.flag;
  int tc = tid & 63, tr = tid >> 6;
  int p0 = tc * 4, bl0 = tr * 8;
  float acc[8][4];
#pragma unroll
  for (int i = 0; i < 8; ++i) { acc[i][0]=0; acc[i][1]=0; acc[i][2]=0; acc[i][3]=0; }

  for (int kc = 0; kc < 32; ++kc) {
    __syncthreads();
    for (int i = tid; i < 32 * 16; i += 256) {
      int bl = i >> 4, kk = i & 15;
      int s = kc * 16 + kk;
      float v = 0.f;
      if (t > 0) {
        long idx = ((long)(half * 32 + bl) * Sn + s) * Tn + (t - 1);
        v = bf ? ldbf((const unsigned short*)P.din, idx) : ((const float*)P.din)[idx];
      }
      x_s[bl * 17 + kk] = v;
    }
    for (int i = tid; i < 16 * 256; i += 256) {
      int kk = i >> 8, p = i & 255;
      W_s[kk * 256 + p] = P.Wp1[(long)(kc * 16 + kk) * 256 + p];
    }
    __syncthreads();
    for (int kk = 0; kk < 16; ++kk) {
      float4 w = *(const float4*)(W_s + kk * 256 + p0);
#pragma unroll
      for (int i = 0; i < 8; ++i) {
        float x = x_s[(bl0 + i) * 17 + kk];
        acc[i][0] += x * w.x; acc[i][1] += x * w.y; acc[i][2] += x * w.z; acc[i][3] += x * w.w;
      }
    }
  }
#pragma unroll
  for (int i = 0; i < 8; ++i)
#pragma unroll
    for (int j = 0; j < 4; ++j) {
      int bl = bl0 + i, p = p0 + j, bg = half * 32 + bl;
      float v = fmaxf(acc[i][j], 0.f);
      unsigned ft = (unsigned)(((long)t * 64 + bg) * 256 + p);
      v = keepmask(k1a, k1b, ft) ? 2.f * v : 0.f;
      h1_s[bl * 258 + p] = v;
      acc[i][j] = 0.f;
    }
  __syncthreads();
  for (int kc = 0; kc < 16; ++kc) {
    __syncthreads();
    for (int i = tid; i < 16 * 256; i += 256) {
      int kk = i >> 8, p = i & 255;
      W_s[kk * 256 + p] = P.Wp2[(long)(kc * 16 + kk) * 256 + p];
    }
    __syncthreads();
    for (int kk = 0; kk < 16; ++kk) {
      float4 w = *(const float4*)(W_s + kk * 256 + p0);
      int s = kc * 16 + kk;
#pragma unroll
      for (int i = 0; i < 8; ++i) {
        float x = h1_s[(bl0 + i) * 258 + s];
        acc[i][0] += x * w.x; acc[i][1] += x * w.y; acc[i][2] += x * w.z; acc[i][3] += x * w.w;
      }
    }
  }
#pragma unroll
  for (int i = 0; i < 8; ++i)
#pragma unroll
    for (int j = 0; j < 4; ++j) {
      int bg = half * 32 + bl0 + i, p = p0 + j;
      float v = fmaxf(acc[i][j], 0.f);
      unsigned ft = (unsigned)(((long)t * 64 + bg) * 256 + p);
      v = keepmask(k2a, k2b, ft) ? 2.f * v : 0.f;
      P.pre_bf[((long)t * 64 + bg) * 256 + p] = f2bf(v);
    }
}

// ---------------- K1: MFMA gate GEMMs with LDS-staged A ----------------
// 512 blocks x 256 thr: bid<256 att gates(t+1), else dec gates(t).
// Block: cg = lb>>2 (64-col group), kc = lb&3 (K chunk). Wave w owns nblk = cg*4+w.
// A tile (64 x SUBK) staged to LDS per substage; B streamed (cached), 2-deep prefetch.
template<bool ATT>
__device__ __forceinline__ void dev_gemm(const Ptrs& P, int t, int lb, unsigned short* a_lds) {
  constexpr int CK    = ATT ? ACK : DCK;      // 448 / 640
  constexpr int SUBK  = CK / 2;               // 224 / 320
  constexpr int NKS   = SUBK / 32;            // 7 / 10
  constexpr int PITCH = SUBK + 8;             // <=2-way LDS bank aliasing (free)
  constexpr int GPR   = SUBK / 8;             // 16B groups per row
  int tid = threadIdx.x;
  int cg = lb >> 2, kc = lb & 3;
  int lane = tid & 63, w = tid >> 6;
  int nblk = cg * 4 + w;
  const unsigned short* PW = ATT ? P.PWatt : P.PWdec;
  const unsigned short* pre_t = P.pre_bf + (long)(t + 1) * 64 * Pn;
  int rlo = lane & 15, khi8 = (lane >> 4) * 8;

  auto aaddr = [&](int kglob, int row) -> const unsigned short* {
    const unsigned short* seg; int stride; int off;
    if (ATT) {
      if (kglob < Pn)           { seg = pre_t;    stride = Pn; off = kglob; }
      else if (kglob < Pn + En) { seg = P.ctx_bf; stride = En; off = kglob - Pn; }
      else                      { seg = P.ah_bf;  stride = An; off = kglob - Pn - En; }
    } else {
      if (kglob < An)           { seg = P.ah_bf;  stride = An; off = kglob; }
      else if (kglob < An + En) { seg = P.ctx_bf; stride = En; off = kglob - An; }
      else                      { seg = P.dh_bf;  stride = Dn; off = kglob - An - En; }
    }
    return seg + (long)row * stride + off;
  };

  f32x4 acc[4];
#pragma unroll
  for (int i = 0; i < 4; ++i) acc[i] = f32x4{0.f, 0.f, 0.f, 0.f};

#pragma unroll
  for (int sub = 0; sub < 2; ++sub) {
    int k0 = kc * CK + sub * SUBK;
    __syncthreads();                            // previous LDS contents consumed
#pragma unroll
    for (int i = 0; i < GPR / 4; ++i) {         // 64*GPR / 256 iterations, static
      int g = tid + i * 256;
      int row = g / GPR, kg = g - row * GPR;
      *(uint4*)(a_lds + row * PITCH + kg * 8) = *(const uint4*)aaddr(k0 + kg * 8, row);
    }
    __syncthreads();
    const unsigned short* bptr = PW + (((long)(k0 >> 5) * 256 + nblk) * 64 + lane) * 8;
    s16x8 bb0 = *(const s16x8*)bptr;
    s16x8 bb1 = *(const s16x8*)(bptr + 131072);  // kblk stride = 256*64*8 elems
#pragma unroll
    for (int kb = 0; kb < NKS; ++kb) {
      s16x8 bcur = (kb & 1) ? bb1 : bb0;
      if (kb + 2 < NKS) {
        s16x8 nb = *(const s16x8*)(bptr + (long)(kb + 2) * 131072);
        if (kb & 1) bb1 = nb; else bb0 = nb;
      }
      int abase = kb * 32 + khi8;
#pragma unroll
      for (int mb = 0; mb < 4; ++mb) {
        s16x8 a = *(const s16x8*)(a_lds + (mb * 16 + rlo) * PITCH + abase);
        acc[mb] = __builtin_amdgcn_mfma_f32_16x16x32_bf16(a, bcur, acc[mb], 0, 0, 0);
      }
    }
  }
  float* Pout = (ATT ? P.Patt : P.Pdec) + (long)kc * 64 * G4A;
  int col = nblk * 16 + rlo, rbase = (lane >> 4) * 4;
#pragma unroll
  for (int mb = 0; mb < 4; ++mb)
#pragma unroll
    for (int r = 0; r < 4; ++r)
      Pout[(long)(mb * 16 + rbase + r) * G4A + col] = acc[mb][r];
}

__global__ __launch_bounds__(256) void k_gemm(Ptrs P, int t) {
  __shared__ __align__(16) unsigned short a_lds[64 * 328];  // dec pitch (42 KB)
  int bid = blockIdx.x;
  if (bid < 256) { if (t + 1 < Tn) dev_gemm<true>(P, t, bid, a_lds); }
  else           { if (t >= 0 && t < Tn) dev_gemm<false>(P, t, bid - 256, a_lds); }
}

// ---------------- K2: pointwise phase ----------------
// blocks 0..63: att LSTM pw(t) + GMM + alpha + ctx.  blocks 64..95: dec LSTM pw(t-1).
template<typename ST>
__global__ __launch_bounds__(256) void k_point(Ptrs P, int t) {
  __shared__ float ah_s[1024];
  __shared__ float red_s[256];
  __shared__ float tanh_s[128];
  __shared__ float bc_s[2];
  __shared__ float alpha_s[176];
  int bid = blockIdx.x, tid = threadIdx.x;
  if (bid < 64) {
    if (t >= Tn) return;
    int b = bid;
    int bf = *P.flag;
    int u0 = tid * 4;
    float gv[4][4];
#pragma unroll
    for (int gt = 0; gt < 4; ++gt) {
      float4 a = *(const float4*)(P.bai + gt * 1024 + u0);
      float4 c = *(const float4*)(P.bah + gt * 1024 + u0);
      gv[gt][0] = a.x + c.x; gv[gt][1] = a.y + c.y; gv[gt][2] = a.z + c.z; gv[gt][3] = a.w + c.w;
    }
#pragma unroll
    for (int kc = 0; kc < ACH; ++kc) {
      const float* pa = P.Patt + ((long)kc * 64 + b) * G4A + u0;
#pragma unroll
      for (int gt = 0; gt < 4; ++gt) {
        float4 v = *(const float4*)(pa + gt * 1024);
        gv[gt][0] += v.x; gv[gt][1] += v.y; gv[gt][2] += v.z; gv[gt][3] += v.w;
      }
    }
    float4 oc = *(const float4*)(P.ac + b * 1024 + u0);
    float oldc[4] = {oc.x, oc.y, oc.z, oc.w};
    float hh[4], cc[4];
#pragma unroll
    for (int i = 0; i < 4; ++i) {
      float ii = sigm(gv[0][i]), ff = sigm(gv[1][i]), oo = sigm(gv[3][i]);
      cc[i] = ff * oldc[i] + ii * tanhf(gv[2][i]);
      hh[i] = oo * tanhf(cc[i]);
      ah_s[u0 + i] = hh[i];
    }
    *(float4*)(P.ac + b * 1024 + u0) = make_float4(cc[0], cc[1], cc[2], cc[3]);
    st4bf(P.ah_bf + b * 1024 + u0, hh[0], hh[1], hh[2], hh[3]);
    __syncthreads();
    // GMM hidden: tanh(ah @ W_g1 + b_g1)
    {
      int g = tid & 127, hf = tid >> 7;
      const float* wg = P.Wg1 + g;
      float a0 = 0.f, a1 = 0.f;
      int ub = hf * 512;
      for (int u = ub; u < ub + 512; u += 2) {
        a0 += ah_s[u]     * wg[(long)u * 128];
        a1 += ah_s[u + 1] * wg[(long)(u + 1) * 128];
      }
      red_s[tid] = a0 + a1;
    }
    __syncthreads();
    if (tid < 128) tanh_s[tid] = tanhf(red_s[tid] + red_s[tid + 128] + P.bg1[tid]);
    __syncthreads();
    if (tid < 64) {
      float tv0 = tanh_s[tid], tv1 = tanh_s[tid + 64];
      float h0 = tv0 * P.Wg2[2 * tid]     + tv1 * P.Wg2[2 * (tid + 64)];
      float h1 = tv0 * P.Wg2[2 * tid + 1] + tv1 * P.Wg2[2 * (tid + 64) + 1];
#pragma unroll
      for (int o = 32; o; o >>= 1) { h0 += __shfl_down(h0, o); h1 += __shfl_down(h1, o); }
      if (tid == 0) {
        float m  = P.mean[b] + expf(h0) * 8.f;
        float sc = expf(h1) * 8.f;
        P.mean[b] = m;
        long pidx = PARAMS_OFF + ((long)b * Tn + t) * 2;
        store_out(P.out, pidx, h0, bf);
        store_out(P.out, pidx + 1, h1, bf);
        bc_s[0] = m; bc_s[1] = sc;
      }
    }
    __syncthreads();
    float m = bc_s[0], sc = bc_s[1];
    int len = P.mlen[b];
    int ci = (int)floorf(fminf(m, 100000.f));
    int l0 = ci - 80; if (l0 < 0) l0 = 0;
    int l1 = ci + 81; if (l1 > len) l1 = len;
    float inv2 = 0.5f / (sc * sc);
    float invZ = 1.f / (2.50662827463100050242f * sc);
    for (int l = l0 + tid; l < l1; l += 256) {
      float d = (float)l - m;
      float al = expf(-d * d * inv2) * invZ;
      alpha_s[l - l0] = al;
      store_out(P.out, ALIGNS_OFF + ((long)b * Tn + t) * Ln + l, al, bf);
    }
    __syncthreads();
    int nl = l1 - l0;
    ST* ctx_all = (ST*)P.ctx_all;
    int e0 = tid * 2;
    float s0 = 0.f, s1 = 0.f;
    if (bf) {
      const unsigned short* mem = (const unsigned short*)P.mem + ((long)b * Ln + l0) * En + e0;
      for (int l = 0; l < nl; ++l) {
        float al = alpha_s[l];
        s0 += al * ldbf(mem, (long)l * En);
        s1 += al * ldbf(mem, (long)l * En + 1);
      }
    } else {
      const float* mem = (const float*)P.mem + ((long)b * Ln + l0) * En + e0;
      for (int l = 0; l < nl; ++l) {
        float al = alpha_s[l];
        s0 += al * mem[(long)l * En];
        s1 += al * mem[(long)l * En + 1];
      }
    }
    unsigned q = (unsigned)f2bf(s0) | ((unsigned)f2bf(s1) << 16);
    *(unsigned*)(P.ctx_bf + b * En + e0) = q;
    st_store(ctx_all, ((long)t * 64 + b) * En + e0, s0);
    st_store(ctx_all, ((long)t * 64 + b) * En + e0 + 1, s1);
  } else {
    if (t == 0) return;
    int bb = bid - 64;
    int b = bb * 2 + (tid >> 7);
    int u0 = (tid & 127) * 8;
    ST* dh_all = (ST*)P.dh_all;
    float gv[4][8];
#pragma unroll
    for (int gt = 0; gt < 4; ++gt) {
      float4 a0 = *(const float4*)(P.bdi + gt * 1024 + u0);
      float4 a1 = *(const float4*)(P.bdi + gt * 1024 + u0 + 4);
      float4 c0 = *(const float4*)(P.bdh + gt * 1024 + u0);
      float4 c1 = *(const float4*)(P.bdh + gt * 1024 + u0 + 4);
      gv[gt][0] = a0.x + c0.x; gv[gt][1] = a0.y + c0.y; gv[gt][2] = a0.z + c0.z; gv[gt][3] = a0.w + c0.w;
      gv[gt][4] = a1.x + c1.x; gv[gt][5] = a1.y + c1.y; gv[gt][6] = a1.z + c1.z; gv[gt][7] = a1.w + c1.w;
    }
#pragma unroll
    for (int kc = 0; kc < DCH; ++kc) {
      const float* pd = P.Pdec + ((long)kc * 64 + b) * G4A + u0;
#pragma unroll
      for (int gt = 0; gt < 4; ++gt) {
        float4 v0 = *(const float4*)(pd + gt * 1024);
        float4 v1 = *(const float4*)(pd + gt * 1024 + 4);
        gv[gt][0] += v0.x; gv[gt][1] += v0.y; gv[gt][2] += v0.z; gv[gt][3] += v0.w;
        gv[gt][4] += v1.x; gv[gt][5] += v1.y; gv[gt][6] += v1.z; gv[gt][7] += v1.w;
      }
    }
    float4 oc0 = *(const float4*)(P.dc + b * 1024 + u0);
    float4 oc1 = *(const float4*)(P.dc + b * 1024 + u0 + 4);
    float oldc[8] = {oc0.x, oc0.y, oc0.z, oc0.w, oc1.x, oc1.y, oc1.z, oc1.w};
    float hh[8], cc[8];
#pragma unroll
    for (int i = 0; i < 8; ++i) {
      float ii = sigm(gv[0][i]), ff = sigm(gv[1][i]), oo = sigm(gv[3][i]);
      cc[i] = ff * oldc[i] + ii * tanhf(gv[2][i]);
      hh[i] = oo * tanhf(cc[i]);
    }
    *(float4*)(P.dc + b * 1024 + u0)     = make_float4(cc[0], cc[1], cc[2], cc[3]);
    *(float4*)(P.dc + b * 1024 + u0 + 4) = make_float4(cc[4], cc[5], cc[6], cc[7]);
    st4bf(P.dh_bf + b * 1024 + u0,     hh[0], hh[1], hh[2], hh[3]);
    st4bf(P.dh_bf + b * 1024 + u0 + 4, hh[4], hh[5], hh[6], hh[7]);
#pragma unroll
    for (int i = 0; i < 8; ++i)
      st_store(dh_all, ((long)(t - 1) * 64 + b) * 1024 + u0 + i, hh[i]);
  }
}

// ---------------- final projection: logits = [dh, ctx] @ W_proj + b ----------------
template<typename ST>
__global__ __launch_bounds__(256) void k_proj(Ptrs P) {
  __shared__ __align__(16) float A_s[64][65];
  __shared__ __align__(16) float W_s[64 * 160];
  int t = blockIdx.x, tid = threadIdx.x;
  int bf = *P.flag;
  const ST* dh_all = (const ST*)P.dh_all;
  const ST* ctx_all = (const ST*)P.ctx_all;
  int tc = tid & 15, tr = tid >> 4;
  int c0 = tc * 10, b0 = tr * 4;
  float acc[4][10];
#pragma unroll
  for (int i = 0; i < 4; ++i)
#pragma unroll
    for (int j = 0; j < 10; ++j) acc[i][j] = 0.f;
  for (int k0 = 0; k0 < KPROJ; k0 += 64) {
    __syncthreads();
    for (int i = tid; i < 64 * 64; i += 256) {
      int b = i >> 6, kk = i & 63;
      int k = k0 + kk;
      float v = (k < Dn) ? st_load(dh_all, ((long)t * 64 + b) * Dn + k)
                         : st_load(ctx_all, ((long)t * 64 + b) * En + (k - Dn));
      A_s[b][kk] = v;
    }
    for (int i = tid; i < 64 * 160; i += 256) {
      int kk = i / 160, c = i - kk * 160;
      W_s[kk * 160 + c] = (c < Vn) ? P.Wpr[(long)(k0 + kk) * Vn + c] : 0.f;
    }
    __syncthreads();
    for (int kk = 0; kk < 64; ++kk) {
      float xs[4];
#pragma unroll
      for (int i = 0; i < 4; ++i) xs[i] = A_s[b0 + i][kk];
#pragma unroll
      for (int j = 0; j < 10; ++j) {
        float w = W_s[kk * 160 + c0 + j];
#pragma unroll
        for (int i = 0; i < 4; ++i) acc[i][j] += xs[i] * w;
      }
    }
  }
#pragma unroll
  for (int i = 0; i < 4; ++i)
#pragma unroll
    for (int j = 0; j < 10; ++j) {
      int c = c0 + j;
      if (c < Vn) {
        int b = b0 + i;
        store_out(P.out, LOGITS_OFF + ((long)b * Tn + t) * Vn + c, acc[i][j] + P.bpr[c], bf);
      }
    }
}

// ---------------- host ----------------
template<typename ST>
static void run_pipeline(const Ptrs& P, hipStream_t stream) {
  k_prenet<<<Tn * 2, 256, 0, stream>>>(P, DK1.a, DK1.b, DK2.a, DK2.b);
  k_gemm<<<512, 256, 0, stream>>>(P, -1);              // prologue: att gates for t=0
  for (int t = 0; t <= Tn; ++t) {
    k_point<ST><<<96, 256, 0, stream>>>(P, t);         // att pw(t) + dec pw(t-1)
    if (t < Tn) k_gemm<<<512, 256, 0, stream>>>(P, t); // att gates(t+1) + dec gates(t)
  }
  k_proj<ST><<<Tn, 256, 0, stream>>>(P);
}

extern "C" void kernel_launch(void* const* d_in, const int* in_sizes, int n_in,
                              void* d_out, int out_size, void* d_ws, size_t ws_size,
                              hipStream_t stream) {
  (void)in_sizes; (void)n_in; (void)out_size;
  char* base = (char*)d_ws;
  int* flag = (int*)base;
  size_t off = 256;
  auto allocf = [&](size_t n) -> float* {
    float* p = (float*)(base + off);
    off += ((n * 4 + 255) / 256) * 256;
    return p;
  };
  auto allocu = [&](size_t n) -> unsigned short* {
    unsigned short* p = (unsigned short*)(base + off);
    off += ((n * 2 + 255) / 256) * 256;
    return p;
  };
  float* Wp1 = allocf(131072);
  float* Wp2 = allocf(65536);
  float* bai = allocf(4096);
  float* bah = allocf(4096);
  float* Wg1 = allocf(131072);
  float* bg1 = allocf(128);
  float* Wg2 = allocf(256);
  float* bdi = allocf(4096);
  float* bdh = allocf(4096);
  float* Wpr = allocf(227328);
  float* bpr = allocf(148);
  unsigned short* PWatt = allocu((size_t)NKB_ATT * 256 * 512);  // bf16 packed weights
  unsigned short* PWdec = allocu((size_t)NKB_DEC * 256 * 512);
  unsigned short* pre_bf = allocu((size_t)Tn * 64 * Pn);
  float* Patt = allocf((size_t)ACH * 64 * G4A);
  float* Pdec = allocf((size_t)DCH * 64 * G4A);
  // zero region: ac, dc, mean (f32) then bf16 mirrors, all contiguous
  float* ac = allocf(65536);
  float* dc = allocf(65536);
  float* mean = allocf(64);
  unsigned short* ah_bf = allocu(65536);
  unsigned short* ctx_bf = allocu(32768);
  unsigned short* dh_bf = allocu(65536);
  size_t fixed = off;
  size_t nDH = (size_t)Tn * 64 * Dn, nCX = (size_t)Tn * 64 * En;
  bool f32tier = (fixed + (nDH + nCX) * 4 <= ws_size);
  bool b16tier = (fixed + (nDH + nCX) * 2 <= ws_size);
  if (!f32tier && !b16tier) return;

  Ptrs P;
  P.Wp1=Wp1; P.Wp2=Wp2; P.bai=bai; P.bah=bah; P.Wg1=Wg1; P.bg1=bg1; P.Wg2=Wg2;
  P.bdi=bdi; P.bdh=bdh; P.Wpr=Wpr; P.bpr=bpr;
  P.PWatt=PWatt; P.PWdec=PWdec; P.pre_bf=pre_bf;
  P.ah_bf=ah_bf; P.ctx_bf=ctx_bf; P.dh_bf=dh_bf;
  P.Patt=Patt; P.Pdec=Pdec; P.ac=ac; P.dc=dc; P.mean=mean;
  size_t esz = f32tier ? 4 : 2;
  P.dh_all  = base + fixed;
  P.ctx_all = base + fixed + nDH * esz;
  P.mem = d_in[0]; P.din = d_in[1]; P.mlen = (const int*)d_in[2];
  P.w_ai = d_in[5]; P.w_ah = d_in[6]; P.w_di = d_in[12]; P.w_dh = d_in[13];
  P.flag = flag; P.out = d_out;

  k_detect<<<1, 256, 0, stream>>>(d_in[0], flag);

  struct CV { const void* s; float* d; long n; };
  const CV cv[11] = {
    {d_in[3], Wp1, 131072}, {d_in[4], Wp2, 65536},
    {d_in[7], bai, 4096}, {d_in[8], bah, 4096},
    {d_in[9], Wg1, 131072}, {d_in[10], bg1, 128}, {d_in[11], Wg2, 256},
    {d_in[14], bdi, 4096}, {d_in[15], bdh, 4096},
    {d_in[16], Wpr, 227328}, {d_in[17], bpr, 148},
  };
  for (int i = 0; i < 11; ++i) {
    long g = (cv[i].n + 255) / 256; if (g > 1024) g = 1024;
    k_convert<<<(int)g, 256, 0, stream>>>(cv[i].s, cv[i].d, cv[i].n, flag);
  }
  k_pack<<<(NKB_ATT + NKB_DEC) * 64, 256, 0, stream>>>(P);
  // ac(65536)+dc(65536)+mean(64) f32 + mirrors 163840 u16 (=81920 words), contiguous
  k_zero_f32<<<512, 256, 0, stream>>>(ac, 131136 + 81920);
  k_zero_aligns<<<2048, 256, 0, stream>>>(d_out, flag);

  if (f32tier) run_pipeline<float>(P, stream);
  else         run_pipeline<unsigned short>(P, stream);
}